// Round 12
// baseline (198.397 us; speedup 1.0000x reference)
//
#include <hip/hip_runtime.h>

typedef unsigned short ushort_t;
typedef unsigned int uint_t;
typedef __bf16 bf16x8 __attribute__((ext_vector_type(8)));
typedef __bf16 bf16x4 __attribute__((ext_vector_type(4)));
typedef float f32x4 __attribute__((ext_vector_type(4)));
typedef ushort_t u16x4 __attribute__((ext_vector_type(4)));

#define NSEQ 4096
#define DIMM 768
#define NQKV 2304
#define HEADS 12
#define LOG2E 1.4426950408889634f

#if __has_builtin(__builtin_amdgcn_exp2f)
#define EXP2(x) __builtin_amdgcn_exp2f(x)
#else
#define EXP2(x) exp2f(x)
#endif

// Fragment-major packing: element (row,k) lives at
//   ((row>>4)*KB + (k>>3))*128 + (row&15)*8 + (k&7)      [KB = K/8]

__device__ __forceinline__ ushort_t f2bf(float f) {
    uint_t u = __float_as_uint(f);
    u = u + 0x7fffu + ((u >> 16) & 1u);
    return (ushort_t)(u >> 16);
}
__device__ __forceinline__ f32x4 zero4() {
    f32x4 v = {0.f, 0.f, 0.f, 0.f};
    return v;
}

// Async global->LDS DMA, 16B per lane. Dest rule (HW): wave-uniform LDS base + lane*16.
// No destination VGPR => the scheduler cannot sink it to a use (rounds 1-3/6/9 failure mode).
__device__ __forceinline__ void gload_lds16(const ushort_t* g, ushort_t* l) {
    __builtin_amdgcn_global_load_lds(
        (const __attribute__((address_space(1))) void*)g,
        (__attribute__((address_space(3))) void*)l, 16, 0, 0);
}

// ---------------- fused prep: X cvt+pack, Wqkv pack, Wout pack (one launch)
__device__ __forceinline__ void pack_w_tile(const float* __restrict__ src,
                                            ushort_t* __restrict__ dst,
                                            int K, int N, int bk, int bn, int t,
                                            ushort_t* Ls) {
    const int tr = t >> 4, tc = t & 15;
#pragma unroll
    for (int i = 0; i < 4; ++i) {
        int r = tr + 16 * i;  // k within tile
        float4 v = *(const float4*)(&src[(size_t)(bk + r) * N + bn + tc * 4]);
        const float* vv = (const float*)&v;
#pragma unroll
        for (int j = 0; j < 4; ++j) Ls[(tc * 4 + j) * 72 + r] = f2bf(vv[j]);
    }
    __syncthreads();
    const int KB = K >> 3;
    const int n = t >> 2;
    const int ks = t & 3;
    const int gn = bn + n;
    size_t base = ((size_t)(gn >> 4) * KB + ((bk + ks * 16) >> 3)) * 128 + (gn & 15) * 8;
    *(uint4*)(&dst[base])       = *(const uint4*)(&Ls[n * 72 + ks * 16]);
    *(uint4*)(&dst[base + 128]) = *(const uint4*)(&Ls[n * 72 + ks * 16 + 8]);
}

#define CVT_BLOCKS   3072                 // TSZ/4/256
#define PW1_BLOCKS   (12 * 36)            // Wqkv 64x64 tiles
#define PW2_BLOCKS   (12 * 12)            // Wout tiles

__global__ __launch_bounds__(256) void prep_kernel(
    const float* __restrict__ X, const float* __restrict__ Wqkv, const float* __restrict__ Wout,
    ushort_t* __restrict__ Ap, ushort_t* __restrict__ Wqp, ushort_t* __restrict__ Wop)
{
    __shared__ ushort_t Ls[64 * 72];
    const int b = blockIdx.x;
    const int t = threadIdx.x;
    if (b < CVT_BLOCKS) {
        int i = b * 256 + t;
        int row = i / (DIMM / 4);
        int k0 = (i - row * (DIMM / 4)) * 4;
        float4 v = *(const float4*)(&X[(size_t)row * DIMM + k0]);
        u16x4 p = { f2bf(v.x), f2bf(v.y), f2bf(v.z), f2bf(v.w) };
        size_t idx = ((size_t)(row >> 4) * (DIMM / 8) + (k0 >> 3)) * 128 + (row & 15) * 8 + (k0 & 7);
        *(u16x4*)(&Ap[idx]) = p;
    } else if (b < CVT_BLOCKS + PW1_BLOCKS) {
        int j = b - CVT_BLOCKS;
        pack_w_tile(Wqkv, Wqp, DIMM, NQKV, (j % 12) * 64, (j / 12) * 64, t, Ls);
    } else {
        int j = b - CVT_BLOCKS - PW1_BLOCKS;
        pack_w_tile(Wout, Wop, DIMM, DIMM, (j % 12) * 64, (j / 12) * 64, t, Ls);
    }
}

// ---------------- QKV GEMM, v2 (r7-proven): m97-style 2-phase LDS-staged double buffer.
#define QKV_STAGE(buf, kt) do {                                          \
    gload_lds16(asrc0 + (kt) * 512, &As[buf][(w * 2)     * 512]);        \
    gload_lds16(asrc1 + (kt) * 512, &As[buf][(w * 2 + 1) * 512]);        \
    gload_lds16(bsrc0 + (kt) * 512, &Bs[buf][(w * 2)     * 512]);        \
    gload_lds16(bsrc1 + (kt) * 512, &Bs[buf][(w * 2 + 1) * 512]);        \
} while (0)

#define QKV_FRAGS(cur) \
    bf16x8 af[4], bfv[4];                                                \
    _Pragma("unroll")                                                    \
    for (int mi = 0; mi < 4; ++mi)                                       \
        af[mi] = *(const bf16x8*)(&As[cur][aoff + mi * 512 + lfr]);      \
    _Pragma("unroll")                                                    \
    for (int nj = 0; nj < 4; ++nj)                                       \
        bfv[nj] = *(const bf16x8*)(&Bs[cur][boff + nj * 512 + lfr]);

__global__ __launch_bounds__(256) void qkv_gemm_kernel(
    const ushort_t* __restrict__ Ap, const ushort_t* __restrict__ Bp,
    ushort_t* __restrict__ Qp, ushort_t* __restrict__ Kp, ushort_t* __restrict__ Vp)
{
    __shared__ ushort_t As[2][4096], Bs[2][4096];
    const int t = threadIdx.x;
    const int lane = t & 63;
    const int w = t >> 6;
    const int m16 = lane & 15;
    const int g = lane >> 4;
    const int wrow = (w >> 1) * 64;
    const int wcol = (w & 1) * 64;
    const int bm = blockIdx.y * 128;
    const int bn = blockIdx.x * 128;
    const int amb = (bm + wrow) >> 4;
    const int bnb = (bn + wcol) >> 4;
    const int bm16 = bm >> 4;
    const int bn16 = bn >> 4;
    const int KB = DIMM / 8;  // 96
    const int which = bn / DIMM;  // 0=Q 1=K 2=V

    const ushort_t* asrc0 = Ap + ((size_t)(bm16 + w * 2)     * KB) * 128 + lane * 8;
    const ushort_t* asrc1 = Ap + ((size_t)(bm16 + w * 2 + 1) * KB) * 128 + lane * 8;
    const ushort_t* bsrc0 = Bp + ((size_t)(bn16 + w * 2)     * KB) * 128 + lane * 8;
    const ushort_t* bsrc1 = Bp + ((size_t)(bn16 + w * 2 + 1) * KB) * 128 + lane * 8;
    const int aoff = (w >> 1) * 2048;   // this wave's 4 A-chunks
    const int boff = (w & 1) * 2048;    // this wave's 4 B-chunks
    const int lfr = g * 128 + m16 * 8;  // fragment lane offset within a chunk

    f32x4 acc[4][4];
#pragma unroll
    for (int i = 0; i < 4; ++i)
#pragma unroll
        for (int j = 0; j < 4; ++j) acc[i][j] = zero4();

    QKV_STAGE(0, 0);
    __syncthreads();   // (compiler drains vmcnt before barrier) tile 0 landed

    if (which < 2) {
        // transposed product: acc rows = out-channel, cols = seq
        for (int kt = 0; kt < 24; ++kt) {
            const int cur = kt & 1;
            if (kt + 1 < 24) QKV_STAGE(cur ^ 1, kt + 1);
            QKV_FRAGS(cur);
#pragma unroll
            for (int mi = 0; mi < 4; ++mi)
#pragma unroll
                for (int nj = 0; nj < 4; ++nj)
                    acc[mi][nj] = __builtin_amdgcn_mfma_f32_16x16x32_bf16(bfv[nj], af[mi], acc[mi][nj], 0, 0, 0);
            __syncthreads();   // prefetch landed + everyone done reading cur
        }
        ushort_t* dst = (which == 0) ? Qp : Kp;
        const float scale = (which == 0) ? LOG2E : 1.0f;
        const int cb = bn - which * DIMM + wcol;
        const int h = cb >> 6;
        const int ghi = g >> 1, glo = g & 1;
#pragma unroll
        for (int mi = 0; mi < 4; ++mi) {
            int sblk = amb + mi;
#pragma unroll
            for (int nj = 0; nj < 4; ++nj) {
                size_t idx = (((size_t)h * 256 + sblk) * 8 + nj * 2 + ghi) * 128 + m16 * 8 + glo * 4;
                u16x4 pk = { f2bf(acc[mi][nj][0] * scale), f2bf(acc[mi][nj][1] * scale),
                             f2bf(acc[mi][nj][2] * scale), f2bf(acc[mi][nj][3] * scale) };
                *(u16x4*)(&dst[idx]) = pk;
            }
        }
    } else {
        // original orientation: acc rows = key, cols = d
        for (int kt = 0; kt < 24; ++kt) {
            const int cur = kt & 1;
            if (kt + 1 < 24) QKV_STAGE(cur ^ 1, kt + 1);
            QKV_FRAGS(cur);
#pragma unroll
            for (int mi = 0; mi < 4; ++mi)
#pragma unroll
                for (int nj = 0; nj < 4; ++nj)
                    acc[mi][nj] = __builtin_amdgcn_mfma_f32_16x16x32_bf16(af[mi], bfv[nj], acc[mi][nj], 0, 0, 0);
            __syncthreads();
        }
        const int cb = bn - 2 * DIMM + wcol;
        const int h = cb >> 6;
        const int ghi = g >> 1, glo = g & 1;
        const int kb8 = (bm + wrow) >> 3;
#pragma unroll
        for (int mi = 0; mi < 4; ++mi) {
#pragma unroll
            for (int nj = 0; nj < 4; ++nj) {
                size_t idx = (((size_t)h * 512 + kb8 + mi * 2 + ghi) * 4 + nj) * 128 + m16 * 8 + glo * 4;
                u16x4 pk = { f2bf(acc[mi][nj][0]), f2bf(acc[mi][nj][1]),
                             f2bf(acc[mi][nj][2]), f2bf(acc[mi][nj][3]) };
                *(u16x4*)(&Vp[idx]) = pk;
            }
        }
    }
}

// ---------------- Flash attention: r10-proven body (best measured 63.5us; FETCH 18.5MB).
// r3 schedule (loads at step top pinned by fence, consumed same step, zero barriers) +
// T1 bijective XCD swizzle. setprio removed (r11: null-to-negative).
#define ATTN_LOADK(dst, ptr) do {                          \
    dst[0][0] = *(const bf16x8*)(ptr);                     \
    dst[0][1] = *(const bf16x8*)((ptr) + 512);             \
    dst[1][0] = *(const bf16x8*)((ptr) + 1024);            \
    dst[1][1] = *(const bf16x8*)((ptr) + 1536);            \
} while (0)

#define ATTN_LOADV(dst, ptr) do {                          \
    dst[0] = *(const bf16x8*)(ptr);                        \
    dst[1] = *(const bf16x8*)((ptr) + 128);                \
    dst[2] = *(const bf16x8*)((ptr) + 256);                \
    dst[3] = *(const bf16x8*)((ptr) + 384);                \
} while (0)

__global__ __launch_bounds__(128, 3) void attn_kernel(
    const ushort_t* __restrict__ Qp, const ushort_t* __restrict__ Kp,
    const ushort_t* __restrict__ Vp, float* __restrict__ Opart, float* __restrict__ Lpart,
    int niter)
{
    __shared__ ushort_t Ps[2][64 * 40];
    const int t = threadIdx.x;
    const int lane = t & 63;
    const int w = t >> 6;           // 0..1
    const int m16 = lane & 15;
    const int g = lane >> 4;

    // T1 bijective XCD swizzle (r10-proven: FETCH 56->18.5MB): XCD c owns a contiguous
    // chunk of the (qb, h, quarter) ordering = 6 heads x one sequence-quarter (3MB <= L2).
    const int cpx = gridDim.x >> 3;                 // 192 (nsplit=4) or 96 (nsplit=2)
    const int d = blockIdx.x;
    const int sid = (d & 7) * cpx + (d >> 3);
    const int qbi  = sid & 31;                      // NSEQ/128 = 32 q-blocks
    const int rem  = sid >> 5;
    const int h    = rem % HEADS;
    const int half = rem / HEADS;                   // sequence quarter (nsplit index)

    const int qb = qbi * 128 + w * 64;   // 64 q-rows per wave
    const int qblk0 = qb >> 4;
    const int kblk0 = half * niter * 4;
    const int vblk0 = half * niter * 8;

    bf16x8 qf[4][2];
#pragma unroll
    for (int mi = 0; mi < 4; ++mi)
#pragma unroll
        for (int kd = 0; kd < 2; ++kd)
            qf[mi][kd] = *(const bf16x8*)(&Qp[(((size_t)h * 256 + qblk0 + mi) * 8 + kd * 4 + g) * 128 + m16 * 8]);

    const ushort_t* kp = Kp + ((size_t)h * 256 + kblk0) * 1024 + g * 128 + m16 * 8;
    const ushort_t* vp = Vp + ((size_t)h * 512 + vblk0) * 512 + g * 512 + m16 * 8;

    f32x4 oacc[4][4];
#pragma unroll
    for (int mi = 0; mi < 4; ++mi)
#pragma unroll
        for (int dj = 0; dj < 4; ++dj) oacc[mi][dj] = zero4();
    f32x4 lacc[4] = {zero4(), zero4(), zero4(), zero4()};

    const int nsteps = niter * 2;   // 32-key steps
    for (int s = 0; s < nsteps; ++s) {
        bf16x8 kf[2][2], vf[4];
        ATTN_LOADK(kf, kp); kp += 2048;
        ATTN_LOADV(vf, vp); vp += 2048;
        asm volatile("" ::: "memory");   // pin load issue at step top; waitcnt lands at use
#pragma unroll
        for (int mi = 0; mi < 4; ++mi) {
            // S^T: rows=keys (nj*16+g*4+r), cols=q (mi*16+m16); p = 2^s (log2e baked into Q)
#pragma unroll
            for (int nj = 0; nj < 2; ++nj) {
                f32x4 st = zero4();
                st = __builtin_amdgcn_mfma_f32_16x16x32_bf16(kf[nj][0], qf[mi][0], st, 0, 0, 0);
                st = __builtin_amdgcn_mfma_f32_16x16x32_bf16(kf[nj][1], qf[mi][1], st, 0, 0, 0);
                f32x4 p;
#pragma unroll
                for (int r = 0; r < 4; ++r) p[r] = EXP2(st[r]);
                lacc[mi] += p;
                bf16x4 pk = { (__bf16)p[0], (__bf16)p[1], (__bf16)p[2], (__bf16)p[3] };
                *(bf16x4*)(&Ps[w][(mi * 16 + m16) * 40 + nj * 16 + g * 4]) = pk;
            }
            // P A-frag (wave-private LDS; in-order DS ops, no barrier)
            bf16x8 pf = *(const bf16x8*)(&Ps[w][(mi * 16 + m16) * 40 + g * 8]);
#pragma unroll
            for (int dj = 0; dj < 4; ++dj)
                oacc[mi][dj] = __builtin_amdgcn_mfma_f32_16x16x32_bf16(pf, vf[dj], oacc[mi][dj], 0, 0, 0);
        }
    }

    float* Oph = Opart + (size_t)half * NSEQ * DIMM;
    float* Lph = Lpart + (size_t)half * HEADS * NSEQ + (size_t)h * NSEQ;
#pragma unroll
    for (int mi = 0; mi < 4; ++mi) {
        float l = (lacc[mi][0] + lacc[mi][1]) + (lacc[mi][2] + lacc[mi][3]);
        l += __shfl_xor(l, 16);
        l += __shfl_xor(l, 32);
        if (g == 0) Lph[qb + mi * 16 + m16] = l;
    }
#pragma unroll
    for (int mi = 0; mi < 4; ++mi) {
#pragma unroll
        for (int r = 0; r < 4; ++r) {
            int row = qb + mi * 16 + g * 4 + r;
#pragma unroll
            for (int dj = 0; dj < 4; ++dj)
                Oph[(size_t)row * DIMM + h * 64 + dj * 16 + m16] = oacc[mi][dj][r];
        }
    }
}

// ---------------- Merge nsplit partials -> Xap frag-major bf16
__global__ __launch_bounds__(256) void merge_kernel(
    const float* __restrict__ Opart, const float* __restrict__ Lpart,
    ushort_t* __restrict__ Xap, int nsplit)
{
    int i = blockIdx.x * 256 + threadIdx.x;
    int row = i / (DIMM / 4);
    int col0 = (i - row * (DIMM / 4)) * 4;
    int h = col0 >> 6;
    float l = 0.f;
    f32x4 o = zero4();
    for (int s = 0; s < nsplit; ++s) {
        l += Lpart[(size_t)s * HEADS * NSEQ + (size_t)h * NSEQ + row];
        f32x4 ov = *(const f32x4*)(&Opart[(size_t)s * NSEQ * DIMM + (size_t)row * DIMM + col0]);
        o += ov;
    }
    float inv = 1.0f / l;
    u16x4 p = { f2bf(o[0] * inv), f2bf(o[1] * inv), f2bf(o[2] * inv), f2bf(o[3] * inv) };
    size_t idx = ((size_t)(row >> 4) * (DIMM / 8) + (col0 >> 3)) * 128 + (row & 15) * 8 + (col0 & 7);
    *(u16x4*)(&Xap[idx]) = p;
}

// ---------------- Output projection, v2: staged-LDS GEMM (clone of the r7-proven
// qkv_gemm structure). The old version used register-destination loads in 64-thread
// blocks (1.5 waves/SIMD) — the exact latency-bound pattern rounds 1-3 identified, and
// the same conversion bought ~5.5us on qkv (r7). 128x128 tiles, grid (6,32)=192 blocks,
// 256 threads; per K-step stage next A(Xap)/B(Wop) 128x32 tiles via global_load_lds,
// one __syncthreads, ds_read_b128 frags, 16 MFMA/wave. Operand values and the epilogue
// mapping (af[mi] x bfv[nj]; col=bn+wcol+nj*16+m16, row=bm+wrow+mi*16+g*4+r) are
// bit-identical to the old kernel — only the load path changed.
__global__ __launch_bounds__(256) void out_gemm_kernel(
    const ushort_t* __restrict__ Ap, const ushort_t* __restrict__ Bp,
    const float* __restrict__ bias, float* __restrict__ out)
{
    __shared__ ushort_t As[2][4096], Bs[2][4096];
    const int t = threadIdx.x;
    const int lane = t & 63;
    const int w = t >> 6;
    const int m16 = lane & 15;
    const int g = lane >> 4;
    const int wrow = (w >> 1) * 64;
    const int wcol = (w & 1) * 64;
    const int bm = blockIdx.y * 128;
    const int bn = blockIdx.x * 128;   // N=768 -> 6 column-blocks
    const int bm16 = bm >> 4;
    const int bn16 = bn >> 4;
    const int KB = DIMM / 8;  // 96

    const ushort_t* asrc0 = Ap + ((size_t)(bm16 + w * 2)     * KB) * 128 + lane * 8;
    const ushort_t* asrc1 = Ap + ((size_t)(bm16 + w * 2 + 1) * KB) * 128 + lane * 8;
    const ushort_t* bsrc0 = Bp + ((size_t)(bn16 + w * 2)     * KB) * 128 + lane * 8;
    const ushort_t* bsrc1 = Bp + ((size_t)(bn16 + w * 2 + 1) * KB) * 128 + lane * 8;
    const int aoff = (w >> 1) * 2048;
    const int boff = (w & 1) * 2048;
    const int lfr = g * 128 + m16 * 8;

    f32x4 acc[4][4];
#pragma unroll
    for (int i = 0; i < 4; ++i)
#pragma unroll
        for (int j = 0; j < 4; ++j) acc[i][j] = zero4();

    QKV_STAGE(0, 0);
    __syncthreads();

    for (int kt = 0; kt < 24; ++kt) {
        const int cur = kt & 1;
        if (kt + 1 < 24) QKV_STAGE(cur ^ 1, kt + 1);
        QKV_FRAGS(cur);
#pragma unroll
        for (int mi = 0; mi < 4; ++mi)
#pragma unroll
            for (int nj = 0; nj < 4; ++nj)
                acc[mi][nj] = __builtin_amdgcn_mfma_f32_16x16x32_bf16(af[mi], bfv[nj], acc[mi][nj], 0, 0, 0);
        __syncthreads();
    }

#pragma unroll
    for (int mi = 0; mi < 4; ++mi) {
#pragma unroll
        for (int nj = 0; nj < 4; ++nj) {
            int col = bn + wcol + nj * 16 + m16;
            float bv = bias[col];
#pragma unroll
            for (int r = 0; r < 4; ++r) {
                int row = bm + wrow + mi * 16 + g * 4 + r;
                out[(size_t)row * DIMM + col] = acc[mi][nj][r] + bv;
            }
        }
    }
}

extern "C" void kernel_launch(void* const* d_in, const int* in_sizes, int n_in,
                              void* d_out, int out_size, void* d_ws, size_t ws_size,
                              hipStream_t stream) {
    (void)in_sizes; (void)n_in; (void)out_size;
    const float* X    = (const float*)d_in[0];
    const float* Wqkv = (const float*)d_in[1];
    const float* Wout = (const float*)d_in[2];
    const float* bout = (const float*)d_in[3];
    float* out = (float*)d_out;

    const size_t TSZ = (size_t)NSEQ * DIMM;  // 3145728
    const size_t fixed = TSZ * 2 * 5 + (size_t)NQKV * DIMM * 2 + (size_t)DIMM * DIMM * 2;
    const size_t per_split = TSZ * 4 + (size_t)HEADS * NSEQ * 4;
    const int nsplit = (ws_size >= fixed + 4 * per_split) ? 4 : 2;

    unsigned char* p = (unsigned char*)d_ws;
    ushort_t* Ap  = (ushort_t*)p; p += TSZ * 2;
    ushort_t* Wqp = (ushort_t*)p; p += (size_t)NQKV * DIMM * 2;
    ushort_t* Wop = (ushort_t*)p; p += (size_t)DIMM * DIMM * 2;
    ushort_t* Qp  = (ushort_t*)p; p += TSZ * 2;
    ushort_t* Kp  = (ushort_t*)p; p += TSZ * 2;
    ushort_t* Vp  = (ushort_t*)p; p += TSZ * 2;
    ushort_t* Xap = (ushort_t*)p; p += TSZ * 2;
    float* Opart  = (float*)p;    p += (size_t)nsplit * TSZ * 4;
    float* Lpart  = (float*)p;

    const int niter = (NSEQ / 64) / nsplit;

    prep_kernel<<<CVT_BLOCKS + PW1_BLOCKS + PW2_BLOCKS, 256, 0, stream>>>(X, Wqkv, Wout, Ap, Wqp, Wop);
    qkv_gemm_kernel<<<dim3(NQKV / 128, NSEQ / 128), 256, 0, stream>>>(Ap, Wqp, Qp, Kp, Vp);
    attn_kernel<<<dim3((NSEQ / 128) * HEADS * nsplit), 128, 0, stream>>>(Qp, Kp, Vp, Opart, Lpart, niter);
    merge_kernel<<<TSZ / 4 / 256, 256, 0, stream>>>(Opart, Lpart, Xap, nsplit);
    out_gemm_kernel<<<dim3(DIMM / 128, NSEQ / 128), 256, 0, stream>>>(Xap, Wop, bout, out);
}

// Round 13
// 187.847 us; speedup vs baseline: 1.0562x; 1.0562x over previous
//
#include <hip/hip_runtime.h>

typedef unsigned short ushort_t;
typedef unsigned int uint_t;
typedef __bf16 bf16x8 __attribute__((ext_vector_type(8)));
typedef __bf16 bf16x4 __attribute__((ext_vector_type(4)));
typedef float f32x4 __attribute__((ext_vector_type(4)));
typedef ushort_t u16x4 __attribute__((ext_vector_type(4)));

#define NSEQ 4096
#define DIMM 768
#define NQKV 2304
#define HEADS 12
#define LOG2E 1.4426950408889634f

#if __has_builtin(__builtin_amdgcn_exp2f)
#define EXP2(x) __builtin_amdgcn_exp2f(x)
#else
#define EXP2(x) exp2f(x)
#endif

// Fragment-major packing: element (row,k) lives at
//   ((row>>4)*KB + (k>>3))*128 + (row&15)*8 + (k&7)      [KB = K/8]

__device__ __forceinline__ ushort_t f2bf(float f) {
    uint_t u = __float_as_uint(f);
    u = u + 0x7fffu + ((u >> 16) & 1u);
    return (ushort_t)(u >> 16);
}
__device__ __forceinline__ f32x4 zero4() {
    f32x4 v = {0.f, 0.f, 0.f, 0.f};
    return v;
}

// Async global->LDS DMA, 16B per lane. Dest rule (HW): wave-uniform LDS base + lane*16.
// No destination VGPR => the scheduler cannot sink it to a use (rounds 1-3/6/9 failure mode).
__device__ __forceinline__ void gload_lds16(const ushort_t* g, ushort_t* l) {
    __builtin_amdgcn_global_load_lds(
        (const __attribute__((address_space(1))) void*)g,
        (__attribute__((address_space(3))) void*)l, 16, 0, 0);
}

// ---------------- fused prep: X cvt+pack, Wqkv pack, Wout pack (one launch)
__device__ __forceinline__ void pack_w_tile(const float* __restrict__ src,
                                            ushort_t* __restrict__ dst,
                                            int K, int N, int bk, int bn, int t,
                                            ushort_t* Ls) {
    const int tr = t >> 4, tc = t & 15;
#pragma unroll
    for (int i = 0; i < 4; ++i) {
        int r = tr + 16 * i;  // k within tile
        float4 v = *(const float4*)(&src[(size_t)(bk + r) * N + bn + tc * 4]);
        const float* vv = (const float*)&v;
#pragma unroll
        for (int j = 0; j < 4; ++j) Ls[(tc * 4 + j) * 72 + r] = f2bf(vv[j]);
    }
    __syncthreads();
    const int KB = K >> 3;
    const int n = t >> 2;
    const int ks = t & 3;
    const int gn = bn + n;
    size_t base = ((size_t)(gn >> 4) * KB + ((bk + ks * 16) >> 3)) * 128 + (gn & 15) * 8;
    *(uint4*)(&dst[base])       = *(const uint4*)(&Ls[n * 72 + ks * 16]);
    *(uint4*)(&dst[base + 128]) = *(const uint4*)(&Ls[n * 72 + ks * 16 + 8]);
}

#define CVT_BLOCKS   3072                 // TSZ/4/256
#define PW1_BLOCKS   (12 * 36)            // Wqkv 64x64 tiles
#define PW2_BLOCKS   (12 * 12)            // Wout tiles

__global__ __launch_bounds__(256) void prep_kernel(
    const float* __restrict__ X, const float* __restrict__ Wqkv, const float* __restrict__ Wout,
    ushort_t* __restrict__ Ap, ushort_t* __restrict__ Wqp, ushort_t* __restrict__ Wop)
{
    __shared__ ushort_t Ls[64 * 72];
    const int b = blockIdx.x;
    const int t = threadIdx.x;
    if (b < CVT_BLOCKS) {
        int i = b * 256 + t;
        int row = i / (DIMM / 4);
        int k0 = (i - row * (DIMM / 4)) * 4;
        float4 v = *(const float4*)(&X[(size_t)row * DIMM + k0]);
        u16x4 p = { f2bf(v.x), f2bf(v.y), f2bf(v.z), f2bf(v.w) };
        size_t idx = ((size_t)(row >> 4) * (DIMM / 8) + (k0 >> 3)) * 128 + (row & 15) * 8 + (k0 & 7);
        *(u16x4*)(&Ap[idx]) = p;
    } else if (b < CVT_BLOCKS + PW1_BLOCKS) {
        int j = b - CVT_BLOCKS;
        pack_w_tile(Wqkv, Wqp, DIMM, NQKV, (j % 12) * 64, (j / 12) * 64, t, Ls);
    } else {
        int j = b - CVT_BLOCKS - PW1_BLOCKS;
        pack_w_tile(Wout, Wop, DIMM, DIMM, (j % 12) * 64, (j / 12) * 64, t, Ls);
    }
}

// ---------------- QKV GEMM, v3: r7-proven staged structure + T1 bijective XCD swizzle.
// Grid flattened to 1D (576 = 8 XCDs x 72); sid=(d&7)*72+(d>>3) gives each XCD a
// contiguous chunk in A-row-major order: 4 A-panels (768KB) + all of B (3.46MB) = 4.2MB
// ~= its private 4MB L2, so the staged-load drains complete at L2 latency instead of
// L3/HBM. Zero arithmetic change vs r7.
#define QKV_STAGE(buf, kt) do {                                          \
    gload_lds16(asrc0 + (kt) * 512, &As[buf][(w * 2)     * 512]);        \
    gload_lds16(asrc1 + (kt) * 512, &As[buf][(w * 2 + 1) * 512]);        \
    gload_lds16(bsrc0 + (kt) * 512, &Bs[buf][(w * 2)     * 512]);        \
    gload_lds16(bsrc1 + (kt) * 512, &Bs[buf][(w * 2 + 1) * 512]);        \
} while (0)

#define QKV_FRAGS(cur) \
    bf16x8 af[4], bfv[4];                                                \
    _Pragma("unroll")                                                    \
    for (int mi = 0; mi < 4; ++mi)                                       \
        af[mi] = *(const bf16x8*)(&As[cur][aoff + mi * 512 + lfr]);      \
    _Pragma("unroll")                                                    \
    for (int nj = 0; nj < 4; ++nj)                                       \
        bfv[nj] = *(const bf16x8*)(&Bs[cur][boff + nj * 512 + lfr]);

__global__ __launch_bounds__(256) void qkv_gemm_kernel(
    const ushort_t* __restrict__ Ap, const ushort_t* __restrict__ Bp,
    ushort_t* __restrict__ Qp, ushort_t* __restrict__ Kp, ushort_t* __restrict__ Vp)
{
    __shared__ ushort_t As[2][4096], Bs[2][4096];
    const int t = threadIdx.x;
    const int lane = t & 63;
    const int w = t >> 6;
    const int m16 = lane & 15;
    const int g = lane >> 4;
    const int wrow = (w >> 1) * 64;
    const int wcol = (w & 1) * 64;

    // T1 bijective XCD swizzle (576 = 8 x 72); sid enumerated x-fastest (bx = sid%18)
    // so one XCD's 72 blocks cover 4 A-row-panels x all 18 B-col-panels.
    const int d = blockIdx.x;
    const int sid = (d & 7) * 72 + (d >> 3);
    const int bx = sid % 18;
    const int by = sid / 18;

    const int bm = by * 128;
    const int bn = bx * 128;
    const int amb = (bm + wrow) >> 4;
    const int bnb = (bn + wcol) >> 4;
    const int bm16 = bm >> 4;
    const int bn16 = bn >> 4;
    const int KB = DIMM / 8;  // 96
    const int which = bn / DIMM;  // 0=Q 1=K 2=V

    const ushort_t* asrc0 = Ap + ((size_t)(bm16 + w * 2)     * KB) * 128 + lane * 8;
    const ushort_t* asrc1 = Ap + ((size_t)(bm16 + w * 2 + 1) * KB) * 128 + lane * 8;
    const ushort_t* bsrc0 = Bp + ((size_t)(bn16 + w * 2)     * KB) * 128 + lane * 8;
    const ushort_t* bsrc1 = Bp + ((size_t)(bn16 + w * 2 + 1) * KB) * 128 + lane * 8;
    const int aoff = (w >> 1) * 2048;   // this wave's 4 A-chunks
    const int boff = (w & 1) * 2048;    // this wave's 4 B-chunks
    const int lfr = g * 128 + m16 * 8;  // fragment lane offset within a chunk

    f32x4 acc[4][4];
#pragma unroll
    for (int i = 0; i < 4; ++i)
#pragma unroll
        for (int j = 0; j < 4; ++j) acc[i][j] = zero4();

    QKV_STAGE(0, 0);
    __syncthreads();   // (compiler drains vmcnt before barrier) tile 0 landed

    if (which < 2) {
        // transposed product: acc rows = out-channel, cols = seq
        for (int kt = 0; kt < 24; ++kt) {
            const int cur = kt & 1;
            if (kt + 1 < 24) QKV_STAGE(cur ^ 1, kt + 1);
            QKV_FRAGS(cur);
#pragma unroll
            for (int mi = 0; mi < 4; ++mi)
#pragma unroll
                for (int nj = 0; nj < 4; ++nj)
                    acc[mi][nj] = __builtin_amdgcn_mfma_f32_16x16x32_bf16(bfv[nj], af[mi], acc[mi][nj], 0, 0, 0);
            __syncthreads();   // prefetch landed + everyone done reading cur
        }
        ushort_t* dst = (which == 0) ? Qp : Kp;
        const float scale = (which == 0) ? LOG2E : 1.0f;
        const int cb = bn - which * DIMM + wcol;
        const int h = cb >> 6;
        const int ghi = g >> 1, glo = g & 1;
#pragma unroll
        for (int mi = 0; mi < 4; ++mi) {
            int sblk = amb + mi;
#pragma unroll
            for (int nj = 0; nj < 4; ++nj) {
                size_t idx = (((size_t)h * 256 + sblk) * 8 + nj * 2 + ghi) * 128 + m16 * 8 + glo * 4;
                u16x4 pk = { f2bf(acc[mi][nj][0] * scale), f2bf(acc[mi][nj][1] * scale),
                             f2bf(acc[mi][nj][2] * scale), f2bf(acc[mi][nj][3] * scale) };
                *(u16x4*)(&dst[idx]) = pk;
            }
        }
    } else {
        // original orientation: acc rows = key, cols = d
        for (int kt = 0; kt < 24; ++kt) {
            const int cur = kt & 1;
            if (kt + 1 < 24) QKV_STAGE(cur ^ 1, kt + 1);
            QKV_FRAGS(cur);
#pragma unroll
            for (int mi = 0; mi < 4; ++mi)
#pragma unroll
                for (int nj = 0; nj < 4; ++nj)
                    acc[mi][nj] = __builtin_amdgcn_mfma_f32_16x16x32_bf16(af[mi], bfv[nj], acc[mi][nj], 0, 0, 0);
            __syncthreads();
        }
        const int cb = bn - 2 * DIMM + wcol;
        const int h = cb >> 6;
        const int ghi = g >> 1, glo = g & 1;
        const int kb8 = (bm + wrow) >> 3;
#pragma unroll
        for (int mi = 0; mi < 4; ++mi) {
#pragma unroll
            for (int nj = 0; nj < 4; ++nj) {
                size_t idx = (((size_t)h * 512 + kb8 + mi * 2 + ghi) * 4 + nj) * 128 + m16 * 8 + glo * 4;
                u16x4 pk = { f2bf(acc[mi][nj][0]), f2bf(acc[mi][nj][1]),
                             f2bf(acc[mi][nj][2]), f2bf(acc[mi][nj][3]) };
                *(u16x4*)(&Vp[idx]) = pk;
            }
        }
    }
}

// ---------------- Flash attention: r10-proven body (best measured 63.5us; FETCH 18.5MB).
// r3 schedule (loads at step top pinned by fence, consumed same step, zero barriers) +
// T1 bijective XCD swizzle. setprio removed (r11: null-to-negative).
#define ATTN_LOADK(dst, ptr) do {                          \
    dst[0][0] = *(const bf16x8*)(ptr);                     \
    dst[0][1] = *(const bf16x8*)((ptr) + 512);             \
    dst[1][0] = *(const bf16x8*)((ptr) + 1024);            \
    dst[1][1] = *(const bf16x8*)((ptr) + 1536);            \
} while (0)

#define ATTN_LOADV(dst, ptr) do {                          \
    dst[0] = *(const bf16x8*)(ptr);                        \
    dst[1] = *(const bf16x8*)((ptr) + 128);                \
    dst[2] = *(const bf16x8*)((ptr) + 256);                \
    dst[3] = *(const bf16x8*)((ptr) + 384);                \
} while (0)

__global__ __launch_bounds__(128, 3) void attn_kernel(
    const ushort_t* __restrict__ Qp, const ushort_t* __restrict__ Kp,
    const ushort_t* __restrict__ Vp, float* __restrict__ Opart, float* __restrict__ Lpart,
    int niter)
{
    __shared__ ushort_t Ps[2][64 * 40];
    const int t = threadIdx.x;
    const int lane = t & 63;
    const int w = t >> 6;           // 0..1
    const int m16 = lane & 15;
    const int g = lane >> 4;

    // T1 bijective XCD swizzle (r10-proven: FETCH 56->18.5MB): XCD c owns a contiguous
    // chunk of the (qb, h, quarter) ordering = 6 heads x one sequence-quarter (3MB <= L2).
    const int cpx = gridDim.x >> 3;                 // 192 (nsplit=4) or 96 (nsplit=2)
    const int d = blockIdx.x;
    const int sid = (d & 7) * cpx + (d >> 3);
    const int qbi  = sid & 31;                      // NSEQ/128 = 32 q-blocks
    const int rem  = sid >> 5;
    const int h    = rem % HEADS;
    const int half = rem / HEADS;                   // sequence quarter (nsplit index)

    const int qb = qbi * 128 + w * 64;   // 64 q-rows per wave
    const int qblk0 = qb >> 4;
    const int kblk0 = half * niter * 4;
    const int vblk0 = half * niter * 8;

    bf16x8 qf[4][2];
#pragma unroll
    for (int mi = 0; mi < 4; ++mi)
#pragma unroll
        for (int kd = 0; kd < 2; ++kd)
            qf[mi][kd] = *(const bf16x8*)(&Qp[(((size_t)h * 256 + qblk0 + mi) * 8 + kd * 4 + g) * 128 + m16 * 8]);

    const ushort_t* kp = Kp + ((size_t)h * 256 + kblk0) * 1024 + g * 128 + m16 * 8;
    const ushort_t* vp = Vp + ((size_t)h * 512 + vblk0) * 512 + g * 512 + m16 * 8;

    f32x4 oacc[4][4];
#pragma unroll
    for (int mi = 0; mi < 4; ++mi)
#pragma unroll
        for (int dj = 0; dj < 4; ++dj) oacc[mi][dj] = zero4();
    f32x4 lacc[4] = {zero4(), zero4(), zero4(), zero4()};

    const int nsteps = niter * 2;   // 32-key steps
    for (int s = 0; s < nsteps; ++s) {
        bf16x8 kf[2][2], vf[4];
        ATTN_LOADK(kf, kp); kp += 2048;
        ATTN_LOADV(vf, vp); vp += 2048;
        asm volatile("" ::: "memory");   // pin load issue at step top; waitcnt lands at use
#pragma unroll
        for (int mi = 0; mi < 4; ++mi) {
            // S^T: rows=keys (nj*16+g*4+r), cols=q (mi*16+m16); p = 2^s (log2e baked into Q)
#pragma unroll
            for (int nj = 0; nj < 2; ++nj) {
                f32x4 st = zero4();
                st = __builtin_amdgcn_mfma_f32_16x16x32_bf16(kf[nj][0], qf[mi][0], st, 0, 0, 0);
                st = __builtin_amdgcn_mfma_f32_16x16x32_bf16(kf[nj][1], qf[mi][1], st, 0, 0, 0);
                f32x4 p;
#pragma unroll
                for (int r = 0; r < 4; ++r) p[r] = EXP2(st[r]);
                lacc[mi] += p;
                bf16x4 pk = { (__bf16)p[0], (__bf16)p[1], (__bf16)p[2], (__bf16)p[3] };
                *(bf16x4*)(&Ps[w][(mi * 16 + m16) * 40 + nj * 16 + g * 4]) = pk;
            }
            // P A-frag (wave-private LDS; in-order DS ops, no barrier)
            bf16x8 pf = *(const bf16x8*)(&Ps[w][(mi * 16 + m16) * 40 + g * 8]);
#pragma unroll
            for (int dj = 0; dj < 4; ++dj)
                oacc[mi][dj] = __builtin_amdgcn_mfma_f32_16x16x32_bf16(pf, vf[dj], oacc[mi][dj], 0, 0, 0);
        }
    }

    float* Oph = Opart + (size_t)half * NSEQ * DIMM;
    float* Lph = Lpart + (size_t)half * HEADS * NSEQ + (size_t)h * NSEQ;
#pragma unroll
    for (int mi = 0; mi < 4; ++mi) {
        float l = (lacc[mi][0] + lacc[mi][1]) + (lacc[mi][2] + lacc[mi][3]);
        l += __shfl_xor(l, 16);
        l += __shfl_xor(l, 32);
        if (g == 0) Lph[qb + mi * 16 + m16] = l;
    }
#pragma unroll
    for (int mi = 0; mi < 4; ++mi) {
#pragma unroll
        for (int r = 0; r < 4; ++r) {
            int row = qb + mi * 16 + g * 4 + r;
#pragma unroll
            for (int dj = 0; dj < 4; ++dj)
                Oph[(size_t)row * DIMM + h * 64 + dj * 16 + m16] = oacc[mi][dj][r];
        }
    }
}

// ---------------- Merge nsplit partials -> Xap frag-major bf16
__global__ __launch_bounds__(256) void merge_kernel(
    const float* __restrict__ Opart, const float* __restrict__ Lpart,
    ushort_t* __restrict__ Xap, int nsplit)
{
    int i = blockIdx.x * 256 + threadIdx.x;
    int row = i / (DIMM / 4);
    int col0 = (i - row * (DIMM / 4)) * 4;
    int h = col0 >> 6;
    float l = 0.f;
    f32x4 o = zero4();
    for (int s = 0; s < nsplit; ++s) {
        l += Lpart[(size_t)s * HEADS * NSEQ + (size_t)h * NSEQ + row];
        f32x4 ov = *(const f32x4*)(&Opart[(size_t)s * NSEQ * DIMM + (size_t)row * DIMM + col0]);
        o += ov;
    }
    float inv = 1.0f / l;
    u16x4 p = { f2bf(o[0] * inv), f2bf(o[1] * inv), f2bf(o[2] * inv), f2bf(o[3] * inv) };
    size_t idx = ((size_t)(row >> 4) * (DIMM / 8) + (col0 >> 3)) * 128 + (row & 15) * 8 + (col0 & 7);
    *(u16x4*)(&Xap[idx]) = p;
}

// ---------------- Output projection: r11-proven version (32x64 wave tiles, 1-wave
// blocks, 1536 blocks of high TLP). r12's staged-LDS clone regressed ~8-10us: with only
// 192 blocks (25% of CUs idle) and 2 barriers/step, the staged structure loses to raw
// TLP on a 4.8 GFLOP kernel. Lesson: staged-LDS wins only when the kernel saturates
// the machine (qkv: 576 blocks); small kernels want many blocks.
__global__ __launch_bounds__(64, 4) void out_gemm_kernel(
    const ushort_t* __restrict__ Ap, const ushort_t* __restrict__ Bp,
    const float* __restrict__ bias, float* __restrict__ out)
{
    const int lane = threadIdx.x & 63;
    const int m16 = lane & 15;
    const int g = lane >> 4;
    const int bm = blockIdx.y * 32;
    const int bn = blockIdx.x * 64;
    const int amb = bm >> 4;
    const int bnb = bn >> 4;
    const int KB = DIMM / 8;  // 96

    f32x4 acc[2][4];
#pragma unroll
    for (int i = 0; i < 2; ++i)
#pragma unroll
        for (int j = 0; j < 4; ++j) acc[i][j] = zero4();

#pragma unroll 2
    for (int kt = 0; kt < 24; ++kt) {
        bf16x8 af[2], bfv[4];
#pragma unroll
        for (int mi = 0; mi < 2; ++mi)
            af[mi] = *(const bf16x8*)(&Ap[((size_t)(amb + mi) * KB + kt * 4 + g) * 128 + m16 * 8]);
#pragma unroll
        for (int nj = 0; nj < 4; ++nj)
            bfv[nj] = *(const bf16x8*)(&Bp[((size_t)(bnb + nj) * KB + kt * 4 + g) * 128 + m16 * 8]);
#pragma unroll
        for (int mi = 0; mi < 2; ++mi)
#pragma unroll
            for (int nj = 0; nj < 4; ++nj)
                acc[mi][nj] = __builtin_amdgcn_mfma_f32_16x16x32_bf16(af[mi], bfv[nj], acc[mi][nj], 0, 0, 0);
    }
#pragma unroll
    for (int mi = 0; mi < 2; ++mi) {
#pragma unroll
        for (int nj = 0; nj < 4; ++nj) {
            int col = bn + nj * 16 + m16;
            float bv = bias[col];
#pragma unroll
            for (int r = 0; r < 4; ++r) {
                int row = bm + mi * 16 + g * 4 + r;
                out[(size_t)row * DIMM + col] = acc[mi][nj][r] + bv;
            }
        }
    }
}

extern "C" void kernel_launch(void* const* d_in, const int* in_sizes, int n_in,
                              void* d_out, int out_size, void* d_ws, size_t ws_size,
                              hipStream_t stream) {
    (void)in_sizes; (void)n_in; (void)out_size;
    const float* X    = (const float*)d_in[0];
    const float* Wqkv = (const float*)d_in[1];
    const float* Wout = (const float*)d_in[2];
    const float* bout = (const float*)d_in[3];
    float* out = (float*)d_out;

    const size_t TSZ = (size_t)NSEQ * DIMM;  // 3145728
    const size_t fixed = TSZ * 2 * 5 + (size_t)NQKV * DIMM * 2 + (size_t)DIMM * DIMM * 2;
    const size_t per_split = TSZ * 4 + (size_t)HEADS * NSEQ * 4;
    const int nsplit = (ws_size >= fixed + 4 * per_split) ? 4 : 2;

    unsigned char* p = (unsigned char*)d_ws;
    ushort_t* Ap  = (ushort_t*)p; p += TSZ * 2;
    ushort_t* Wqp = (ushort_t*)p; p += (size_t)NQKV * DIMM * 2;
    ushort_t* Wop = (ushort_t*)p; p += (size_t)DIMM * DIMM * 2;
    ushort_t* Qp  = (ushort_t*)p; p += TSZ * 2;
    ushort_t* Kp  = (ushort_t*)p; p += TSZ * 2;
    ushort_t* Vp  = (ushort_t*)p; p += TSZ * 2;
    ushort_t* Xap = (ushort_t*)p; p += TSZ * 2;
    float* Opart  = (float*)p;    p += (size_t)nsplit * TSZ * 4;
    float* Lpart  = (float*)p;

    const int niter = (NSEQ / 64) / nsplit;

    prep_kernel<<<CVT_BLOCKS + PW1_BLOCKS + PW2_BLOCKS, 256, 0, stream>>>(X, Wqkv, Wout, Ap, Wqp, Wop);
    qkv_gemm_kernel<<<dim3(576), 256, 0, stream>>>(Ap, Wqp, Qp, Kp, Vp);
    attn_kernel<<<dim3((NSEQ / 128) * HEADS * nsplit), 128, 0, stream>>>(Qp, Kp, Vp, Opart, Lpart, niter);
    merge_kernel<<<TSZ / 4 / 256, 256, 0, stream>>>(Opart, Lpart, Xap, nsplit);
    out_gemm_kernel<<<dim3(DIMM / 64, NSEQ / 32), 64, 0, stream>>>(Xap, Wop, bout, out);
}

// Round 14
// 187.819 us; speedup vs baseline: 1.0563x; 1.0001x over previous
//
#include <hip/hip_runtime.h>

typedef unsigned short ushort_t;
typedef unsigned int uint_t;
typedef __bf16 bf16x8 __attribute__((ext_vector_type(8)));
typedef __bf16 bf16x4 __attribute__((ext_vector_type(4)));
typedef float f32x4 __attribute__((ext_vector_type(4)));
typedef ushort_t u16x4 __attribute__((ext_vector_type(4)));

#define NSEQ 4096
#define DIMM 768
#define NQKV 2304
#define HEADS 12
#define LOG2E 1.4426950408889634f

#if __has_builtin(__builtin_amdgcn_exp2f)
#define EXP2(x) __builtin_amdgcn_exp2f(x)
#else
#define EXP2(x) exp2f(x)
#endif

// Fragment-major packing: element (row,k) lives at
//   ((row>>4)*KB + (k>>3))*128 + (row&15)*8 + (k&7)      [KB = K/8]

__device__ __forceinline__ ushort_t f2bf(float f) {
    uint_t u = __float_as_uint(f);
    u = u + 0x7fffu + ((u >> 16) & 1u);
    return (ushort_t)(u >> 16);
}
__device__ __forceinline__ float bf2f(ushort_t v) {
    return __uint_as_float(((uint_t)v) << 16);
}
__device__ __forceinline__ f32x4 zero4() {
    f32x4 v = {0.f, 0.f, 0.f, 0.f};
    return v;
}

// Async global->LDS DMA, 16B per lane. Dest rule (HW): wave-uniform LDS base + lane*16.
// No destination VGPR => the scheduler cannot sink it to a use (rounds 1-3/6/9 failure mode).
__device__ __forceinline__ void gload_lds16(const ushort_t* g, ushort_t* l) {
    __builtin_amdgcn_global_load_lds(
        (const __attribute__((address_space(1))) void*)g,
        (__attribute__((address_space(3))) void*)l, 16, 0, 0);
}

// ---------------- fused prep: X cvt+pack, Wqkv pack, Wout pack (one launch)
__device__ __forceinline__ void pack_w_tile(const float* __restrict__ src,
                                            ushort_t* __restrict__ dst,
                                            int K, int N, int bk, int bn, int t,
                                            ushort_t* Ls) {
    const int tr = t >> 4, tc = t & 15;
#pragma unroll
    for (int i = 0; i < 4; ++i) {
        int r = tr + 16 * i;  // k within tile
        float4 v = *(const float4*)(&src[(size_t)(bk + r) * N + bn + tc * 4]);
        const float* vv = (const float*)&v;
#pragma unroll
        for (int j = 0; j < 4; ++j) Ls[(tc * 4 + j) * 72 + r] = f2bf(vv[j]);
    }
    __syncthreads();
    const int KB = K >> 3;
    const int n = t >> 2;
    const int ks = t & 3;
    const int gn = bn + n;
    size_t base = ((size_t)(gn >> 4) * KB + ((bk + ks * 16) >> 3)) * 128 + (gn & 15) * 8;
    *(uint4*)(&dst[base])       = *(const uint4*)(&Ls[n * 72 + ks * 16]);
    *(uint4*)(&dst[base + 128]) = *(const uint4*)(&Ls[n * 72 + ks * 16 + 8]);
}

#define CVT_BLOCKS   3072                 // TSZ/4/256
#define PW1_BLOCKS   (12 * 36)            // Wqkv 64x64 tiles
#define PW2_BLOCKS   (12 * 12)            // Wout tiles

__global__ __launch_bounds__(256) void prep_kernel(
    const float* __restrict__ X, const float* __restrict__ Wqkv, const float* __restrict__ Wout,
    ushort_t* __restrict__ Ap, ushort_t* __restrict__ Wqp, ushort_t* __restrict__ Wop)
{
    __shared__ ushort_t Ls[64 * 72];
    const int b = blockIdx.x;
    const int t = threadIdx.x;
    if (b < CVT_BLOCKS) {
        int i = b * 256 + t;
        int row = i / (DIMM / 4);
        int k0 = (i - row * (DIMM / 4)) * 4;
        float4 v = *(const float4*)(&X[(size_t)row * DIMM + k0]);
        u16x4 p = { f2bf(v.x), f2bf(v.y), f2bf(v.z), f2bf(v.w) };
        size_t idx = ((size_t)(row >> 4) * (DIMM / 8) + (k0 >> 3)) * 128 + (row & 15) * 8 + (k0 & 7);
        *(u16x4*)(&Ap[idx]) = p;
    } else if (b < CVT_BLOCKS + PW1_BLOCKS) {
        int j = b - CVT_BLOCKS;
        pack_w_tile(Wqkv, Wqp, DIMM, NQKV, (j % 12) * 64, (j / 12) * 64, t, Ls);
    } else {
        int j = b - CVT_BLOCKS - PW1_BLOCKS;
        pack_w_tile(Wout, Wop, DIMM, DIMM, (j % 12) * 64, (j / 12) * 64, t, Ls);
    }
}

// ---------------- QKV GEMM, v3 (r13-proven): staged structure + T1 bijective XCD swizzle.
#define QKV_STAGE(buf, kt) do {                                          \
    gload_lds16(asrc0 + (kt) * 512, &As[buf][(w * 2)     * 512]);        \
    gload_lds16(asrc1 + (kt) * 512, &As[buf][(w * 2 + 1) * 512]);        \
    gload_lds16(bsrc0 + (kt) * 512, &Bs[buf][(w * 2)     * 512]);        \
    gload_lds16(bsrc1 + (kt) * 512, &Bs[buf][(w * 2 + 1) * 512]);        \
} while (0)

#define QKV_FRAGS(cur) \
    bf16x8 af[4], bfv[4];                                                \
    _Pragma("unroll")                                                    \
    for (int mi = 0; mi < 4; ++mi)                                       \
        af[mi] = *(const bf16x8*)(&As[cur][aoff + mi * 512 + lfr]);      \
    _Pragma("unroll")                                                    \
    for (int nj = 0; nj < 4; ++nj)                                       \
        bfv[nj] = *(const bf16x8*)(&Bs[cur][boff + nj * 512 + lfr]);

__global__ __launch_bounds__(256) void qkv_gemm_kernel(
    const ushort_t* __restrict__ Ap, const ushort_t* __restrict__ Bp,
    ushort_t* __restrict__ Qp, ushort_t* __restrict__ Kp, ushort_t* __restrict__ Vp)
{
    __shared__ ushort_t As[2][4096], Bs[2][4096];
    const int t = threadIdx.x;
    const int lane = t & 63;
    const int w = t >> 6;
    const int m16 = lane & 15;
    const int g = lane >> 4;
    const int wrow = (w >> 1) * 64;
    const int wcol = (w & 1) * 64;

    // T1 bijective XCD swizzle (576 = 8 x 72)
    const int d = blockIdx.x;
    const int sid = (d & 7) * 72 + (d >> 3);
    const int bx = sid % 18;
    const int by = sid / 18;

    const int bm = by * 128;
    const int bn = bx * 128;
    const int amb = (bm + wrow) >> 4;
    const int bnb = (bn + wcol) >> 4;
    const int bm16 = bm >> 4;
    const int bn16 = bn >> 4;
    const int KB = DIMM / 8;  // 96
    const int which = bn / DIMM;  // 0=Q 1=K 2=V

    const ushort_t* asrc0 = Ap + ((size_t)(bm16 + w * 2)     * KB) * 128 + lane * 8;
    const ushort_t* asrc1 = Ap + ((size_t)(bm16 + w * 2 + 1) * KB) * 128 + lane * 8;
    const ushort_t* bsrc0 = Bp + ((size_t)(bn16 + w * 2)     * KB) * 128 + lane * 8;
    const ushort_t* bsrc1 = Bp + ((size_t)(bn16 + w * 2 + 1) * KB) * 128 + lane * 8;
    const int aoff = (w >> 1) * 2048;   // this wave's 4 A-chunks
    const int boff = (w & 1) * 2048;    // this wave's 4 B-chunks
    const int lfr = g * 128 + m16 * 8;  // fragment lane offset within a chunk

    f32x4 acc[4][4];
#pragma unroll
    for (int i = 0; i < 4; ++i)
#pragma unroll
        for (int j = 0; j < 4; ++j) acc[i][j] = zero4();

    QKV_STAGE(0, 0);
    __syncthreads();   // (compiler drains vmcnt before barrier) tile 0 landed

    if (which < 2) {
        // transposed product: acc rows = out-channel, cols = seq
        for (int kt = 0; kt < 24; ++kt) {
            const int cur = kt & 1;
            if (kt + 1 < 24) QKV_STAGE(cur ^ 1, kt + 1);
            QKV_FRAGS(cur);
#pragma unroll
            for (int mi = 0; mi < 4; ++mi)
#pragma unroll
                for (int nj = 0; nj < 4; ++nj)
                    acc[mi][nj] = __builtin_amdgcn_mfma_f32_16x16x32_bf16(bfv[nj], af[mi], acc[mi][nj], 0, 0, 0);
            __syncthreads();   // prefetch landed + everyone done reading cur
        }
        ushort_t* dst = (which == 0) ? Qp : Kp;
        const float scale = (which == 0) ? LOG2E : 1.0f;
        const int cb = bn - which * DIMM + wcol;
        const int h = cb >> 6;
        const int ghi = g >> 1, glo = g & 1;
#pragma unroll
        for (int mi = 0; mi < 4; ++mi) {
            int sblk = amb + mi;
#pragma unroll
            for (int nj = 0; nj < 4; ++nj) {
                size_t idx = (((size_t)h * 256 + sblk) * 8 + nj * 2 + ghi) * 128 + m16 * 8 + glo * 4;
                u16x4 pk = { f2bf(acc[mi][nj][0] * scale), f2bf(acc[mi][nj][1] * scale),
                             f2bf(acc[mi][nj][2] * scale), f2bf(acc[mi][nj][3] * scale) };
                *(u16x4*)(&dst[idx]) = pk;
            }
        }
    } else {
        // original orientation: acc rows = key, cols = d
        for (int kt = 0; kt < 24; ++kt) {
            const int cur = kt & 1;
            if (kt + 1 < 24) QKV_STAGE(cur ^ 1, kt + 1);
            QKV_FRAGS(cur);
#pragma unroll
            for (int mi = 0; mi < 4; ++mi)
#pragma unroll
                for (int nj = 0; nj < 4; ++nj)
                    acc[mi][nj] = __builtin_amdgcn_mfma_f32_16x16x32_bf16(af[mi], bfv[nj], acc[mi][nj], 0, 0, 0);
            __syncthreads();
        }
        const int cb = bn - 2 * DIMM + wcol;
        const int h = cb >> 6;
        const int ghi = g >> 1, glo = g & 1;
        const int kb8 = (bm + wrow) >> 3;
#pragma unroll
        for (int mi = 0; mi < 4; ++mi) {
#pragma unroll
            for (int nj = 0; nj < 4; ++nj) {
                size_t idx = (((size_t)h * 512 + kb8 + mi * 2 + ghi) * 4 + nj) * 128 + m16 * 8 + glo * 4;
                u16x4 pk = { f2bf(acc[mi][nj][0]), f2bf(acc[mi][nj][1]),
                             f2bf(acc[mi][nj][2]), f2bf(acc[mi][nj][3]) };
                *(u16x4*)(&Vp[idx]) = pk;
            }
        }
    }
}

// ---------------- Flash attention: r10-proven body + bf16 Opart partials.
// r3 schedule (loads at step top pinned by fence, consumed same step, zero barriers) +
// T1 bijective XCD swizzle (FETCH 56->18.5MB proven). NEW: O-partials stored as bf16 —
// the merged O is rounded to bf16 (Xap) before the out-projection anyway, so quantizing
// each partial adds error of the same order; halves attn write traffic (50->26MB) and
// merge read traffic (48->24MB).
#define ATTN_LOADK(dst, ptr) do {                          \
    dst[0][0] = *(const bf16x8*)(ptr);                     \
    dst[0][1] = *(const bf16x8*)((ptr) + 512);             \
    dst[1][0] = *(const bf16x8*)((ptr) + 1024);            \
    dst[1][1] = *(const bf16x8*)((ptr) + 1536);            \
} while (0)

#define ATTN_LOADV(dst, ptr) do {                          \
    dst[0] = *(const bf16x8*)(ptr);                        \
    dst[1] = *(const bf16x8*)((ptr) + 128);                \
    dst[2] = *(const bf16x8*)((ptr) + 256);                \
    dst[3] = *(const bf16x8*)((ptr) + 384);                \
} while (0)

__global__ __launch_bounds__(128, 3) void attn_kernel(
    const ushort_t* __restrict__ Qp, const ushort_t* __restrict__ Kp,
    const ushort_t* __restrict__ Vp, ushort_t* __restrict__ Opart, float* __restrict__ Lpart,
    int niter)
{
    __shared__ ushort_t Ps[2][64 * 40];
    const int t = threadIdx.x;
    const int lane = t & 63;
    const int w = t >> 6;           // 0..1
    const int m16 = lane & 15;
    const int g = lane >> 4;

    // T1 bijective XCD swizzle (r10-proven): XCD c owns a contiguous chunk of the
    // (qb, h, quarter) ordering = 6 heads x one sequence-quarter (3MB <= L2).
    const int cpx = gridDim.x >> 3;                 // 192 (nsplit=4) or 96 (nsplit=2)
    const int d = blockIdx.x;
    const int sid = (d & 7) * cpx + (d >> 3);
    const int qbi  = sid & 31;                      // NSEQ/128 = 32 q-blocks
    const int rem  = sid >> 5;
    const int h    = rem % HEADS;
    const int half = rem / HEADS;                   // sequence quarter (nsplit index)

    const int qb = qbi * 128 + w * 64;   // 64 q-rows per wave
    const int qblk0 = qb >> 4;
    const int kblk0 = half * niter * 4;
    const int vblk0 = half * niter * 8;

    bf16x8 qf[4][2];
#pragma unroll
    for (int mi = 0; mi < 4; ++mi)
#pragma unroll
        for (int kd = 0; kd < 2; ++kd)
            qf[mi][kd] = *(const bf16x8*)(&Qp[(((size_t)h * 256 + qblk0 + mi) * 8 + kd * 4 + g) * 128 + m16 * 8]);

    const ushort_t* kp = Kp + ((size_t)h * 256 + kblk0) * 1024 + g * 128 + m16 * 8;
    const ushort_t* vp = Vp + ((size_t)h * 512 + vblk0) * 512 + g * 512 + m16 * 8;

    f32x4 oacc[4][4];
#pragma unroll
    for (int mi = 0; mi < 4; ++mi)
#pragma unroll
        for (int dj = 0; dj < 4; ++dj) oacc[mi][dj] = zero4();
    f32x4 lacc[4] = {zero4(), zero4(), zero4(), zero4()};

    const int nsteps = niter * 2;   // 32-key steps
    for (int s = 0; s < nsteps; ++s) {
        bf16x8 kf[2][2], vf[4];
        ATTN_LOADK(kf, kp); kp += 2048;
        ATTN_LOADV(vf, vp); vp += 2048;
        asm volatile("" ::: "memory");   // pin load issue at step top; waitcnt lands at use
#pragma unroll
        for (int mi = 0; mi < 4; ++mi) {
            // S^T: rows=keys (nj*16+g*4+r), cols=q (mi*16+m16); p = 2^s (log2e baked into Q)
#pragma unroll
            for (int nj = 0; nj < 2; ++nj) {
                f32x4 st = zero4();
                st = __builtin_amdgcn_mfma_f32_16x16x32_bf16(kf[nj][0], qf[mi][0], st, 0, 0, 0);
                st = __builtin_amdgcn_mfma_f32_16x16x32_bf16(kf[nj][1], qf[mi][1], st, 0, 0, 0);
                f32x4 p;
#pragma unroll
                for (int r = 0; r < 4; ++r) p[r] = EXP2(st[r]);
                lacc[mi] += p;
                bf16x4 pk = { (__bf16)p[0], (__bf16)p[1], (__bf16)p[2], (__bf16)p[3] };
                *(bf16x4*)(&Ps[w][(mi * 16 + m16) * 40 + nj * 16 + g * 4]) = pk;
            }
            // P A-frag (wave-private LDS; in-order DS ops, no barrier)
            bf16x8 pf = *(const bf16x8*)(&Ps[w][(mi * 16 + m16) * 40 + g * 8]);
#pragma unroll
            for (int dj = 0; dj < 4; ++dj)
                oacc[mi][dj] = __builtin_amdgcn_mfma_f32_16x16x32_bf16(pf, vf[dj], oacc[mi][dj], 0, 0, 0);
        }
    }

    ushort_t* Oph = Opart + (size_t)half * NSEQ * DIMM;
    float* Lph = Lpart + (size_t)half * HEADS * NSEQ + (size_t)h * NSEQ;
#pragma unroll
    for (int mi = 0; mi < 4; ++mi) {
        float l = (lacc[mi][0] + lacc[mi][1]) + (lacc[mi][2] + lacc[mi][3]);
        l += __shfl_xor(l, 16);
        l += __shfl_xor(l, 32);
        if (g == 0) Lph[qb + mi * 16 + m16] = l;
    }
#pragma unroll
    for (int mi = 0; mi < 4; ++mi) {
#pragma unroll
        for (int r = 0; r < 4; ++r) {
            int row = qb + mi * 16 + g * 4 + r;
#pragma unroll
            for (int dj = 0; dj < 4; ++dj)
                Oph[(size_t)row * DIMM + h * 64 + dj * 16 + m16] = f2bf(oacc[mi][dj][r]);
        }
    }
}

// ---------------- Merge nsplit bf16 partials -> Xap frag-major bf16
__global__ __launch_bounds__(256) void merge_kernel(
    const ushort_t* __restrict__ Opart, const float* __restrict__ Lpart,
    ushort_t* __restrict__ Xap, int nsplit)
{
    int i = blockIdx.x * 256 + threadIdx.x;
    int row = i / (DIMM / 4);
    int col0 = (i - row * (DIMM / 4)) * 4;
    int h = col0 >> 6;
    float l = 0.f;
    f32x4 o = zero4();
    for (int s = 0; s < nsplit; ++s) {
        l += Lpart[(size_t)s * HEADS * NSEQ + (size_t)h * NSEQ + row];
        u16x4 ov = *(const u16x4*)(&Opart[(size_t)s * NSEQ * DIMM + (size_t)row * DIMM + col0]);
#pragma unroll
        for (int j = 0; j < 4; ++j) o[j] += bf2f(ov[j]);
    }
    float inv = 1.0f / l;
    u16x4 p = { f2bf(o[0] * inv), f2bf(o[1] * inv), f2bf(o[2] * inv), f2bf(o[3] * inv) };
    size_t idx = ((size_t)(row >> 4) * (DIMM / 8) + (col0 >> 3)) * 128 + (row & 15) * 8 + (col0 & 7);
    *(u16x4*)(&Xap[idx]) = p;
}

// ---------------- Output projection: r11-proven version (32x64 wave tiles, 1-wave
// blocks, 1536 blocks of high TLP; r12 proved staged-LDS loses here).
__global__ __launch_bounds__(64, 4) void out_gemm_kernel(
    const ushort_t* __restrict__ Ap, const ushort_t* __restrict__ Bp,
    const float* __restrict__ bias, float* __restrict__ out)
{
    const int lane = threadIdx.x & 63;
    const int m16 = lane & 15;
    const int g = lane >> 4;
    const int bm = blockIdx.y * 32;
    const int bn = blockIdx.x * 64;
    const int amb = bm >> 4;
    const int bnb = bn >> 4;
    const int KB = DIMM / 8;  // 96

    f32x4 acc[2][4];
#pragma unroll
    for (int i = 0; i < 2; ++i)
#pragma unroll
        for (int j = 0; j < 4; ++j) acc[i][j] = zero4();

#pragma unroll 2
    for (int kt = 0; kt < 24; ++kt) {
        bf16x8 af[2], bfv[4];
#pragma unroll
        for (int mi = 0; mi < 2; ++mi)
            af[mi] = *(const bf16x8*)(&Ap[((size_t)(amb + mi) * KB + kt * 4 + g) * 128 + m16 * 8]);
#pragma unroll
        for (int nj = 0; nj < 4; ++nj)
            bfv[nj] = *(const bf16x8*)(&Bp[((size_t)(bnb + nj) * KB + kt * 4 + g) * 128 + m16 * 8]);
#pragma unroll
        for (int mi = 0; mi < 2; ++mi)
#pragma unroll
            for (int nj = 0; nj < 4; ++nj)
                acc[mi][nj] = __builtin_amdgcn_mfma_f32_16x16x32_bf16(af[mi], bfv[nj], acc[mi][nj], 0, 0, 0);
    }
#pragma unroll
    for (int mi = 0; mi < 2; ++mi) {
#pragma unroll
        for (int nj = 0; nj < 4; ++nj) {
            int col = bn + nj * 16 + m16;
            float bv = bias[col];
#pragma unroll
            for (int r = 0; r < 4; ++r) {
                int row = bm + mi * 16 + g * 4 + r;
                out[(size_t)row * DIMM + col] = acc[mi][nj][r] + bv;
            }
        }
    }
}

extern "C" void kernel_launch(void* const* d_in, const int* in_sizes, int n_in,
                              void* d_out, int out_size, void* d_ws, size_t ws_size,
                              hipStream_t stream) {
    (void)in_sizes; (void)n_in; (void)out_size;
    const float* X    = (const float*)d_in[0];
    const float* Wqkv = (const float*)d_in[1];
    const float* Wout = (const float*)d_in[2];
    const float* bout = (const float*)d_in[3];
    float* out = (float*)d_out;

    const size_t TSZ = (size_t)NSEQ * DIMM;  // 3145728
    const size_t fixed = TSZ * 2 * 5 + (size_t)NQKV * DIMM * 2 + (size_t)DIMM * DIMM * 2;
    const size_t per_split = TSZ * 2 + (size_t)HEADS * NSEQ * 4;   // bf16 Opart + f32 Lpart
    const int nsplit = (ws_size >= fixed + 4 * per_split) ? 4 : 2;

    unsigned char* p = (unsigned char*)d_ws;
    ushort_t* Ap  = (ushort_t*)p; p += TSZ * 2;
    ushort_t* Wqp = (ushort_t*)p; p += (size_t)NQKV * DIMM * 2;
    ushort_t* Wop = (ushort_t*)p; p += (size_t)DIMM * DIMM * 2;
    ushort_t* Qp  = (ushort_t*)p; p += TSZ * 2;
    ushort_t* Kp  = (ushort_t*)p; p += TSZ * 2;
    ushort_t* Vp  = (ushort_t*)p; p += TSZ * 2;
    ushort_t* Xap = (ushort_t*)p; p += TSZ * 2;
    ushort_t* Opart = (ushort_t*)p; p += (size_t)nsplit * TSZ * 2;
    float* Lpart  = (float*)p;

    const int niter = (NSEQ / 64) / nsplit;

    prep_kernel<<<CVT_BLOCKS + PW1_BLOCKS + PW2_BLOCKS, 256, 0, stream>>>(X, Wqkv, Wout, Ap, Wqp, Wop);
    qkv_gemm_kernel<<<dim3(576), 256, 0, stream>>>(Ap, Wqp, Qp, Kp, Vp);
    attn_kernel<<<dim3((NSEQ / 128) * HEADS * nsplit), 128, 0, stream>>>(Qp, Kp, Vp, Opart, Lpart, niter);
    merge_kernel<<<TSZ / 4 / 256, 256, 0, stream>>>(Opart, Lpart, Xap, nsplit);
    out_gemm_kernel<<<dim3(DIMM / 64, NSEQ / 32), 64, 0, stream>>>(Xap, Wop, bout, out);
}

// Round 15
// 185.239 us; speedup vs baseline: 1.0710x; 1.0139x over previous
//
#include <hip/hip_runtime.h>

typedef unsigned short ushort_t;
typedef unsigned int uint_t;
typedef __bf16 bf16x8 __attribute__((ext_vector_type(8)));
typedef __bf16 bf16x4 __attribute__((ext_vector_type(4)));
typedef float f32x4 __attribute__((ext_vector_type(4)));
typedef ushort_t u16x4 __attribute__((ext_vector_type(4)));

#define NSEQ 4096
#define DIMM 768
#define NQKV 2304
#define HEADS 12
#define LOG2E 1.4426950408889634f

#if __has_builtin(__builtin_amdgcn_exp2f)
#define EXP2(x) __builtin_amdgcn_exp2f(x)
#else
#define EXP2(x) exp2f(x)
#endif

// Fragment-major packing: element (row,k) lives at
//   ((row>>4)*KB + (k>>3))*128 + (row&15)*8 + (k&7)      [KB = K/8]

__device__ __forceinline__ ushort_t f2bf(float f) {
    uint_t u = __float_as_uint(f);
    u = u + 0x7fffu + ((u >> 16) & 1u);
    return (ushort_t)(u >> 16);
}
__device__ __forceinline__ float bf2f(ushort_t v) {
    return __uint_as_float(((uint_t)v) << 16);
}
__device__ __forceinline__ f32x4 zero4() {
    f32x4 v = {0.f, 0.f, 0.f, 0.f};
    return v;
}

// Async global->LDS DMA, 16B per lane. Dest rule (HW): wave-uniform LDS base + lane*16.
// No destination VGPR => the scheduler cannot sink it to a use (rounds 1-3/6/9 failure mode).
__device__ __forceinline__ void gload_lds16(const ushort_t* g, ushort_t* l) {
    __builtin_amdgcn_global_load_lds(
        (const __attribute__((address_space(1))) void*)g,
        (__attribute__((address_space(3))) void*)l, 16, 0, 0);
}

// ---------------- fused prep: X cvt+pack, Wqkv pack, Wout pack (one launch)
__device__ __forceinline__ void pack_w_tile(const float* __restrict__ src,
                                            ushort_t* __restrict__ dst,
                                            int K, int N, int bk, int bn, int t,
                                            ushort_t* Ls) {
    const int tr = t >> 4, tc = t & 15;
#pragma unroll
    for (int i = 0; i < 4; ++i) {
        int r = tr + 16 * i;  // k within tile
        float4 v = *(const float4*)(&src[(size_t)(bk + r) * N + bn + tc * 4]);
        const float* vv = (const float*)&v;
#pragma unroll
        for (int j = 0; j < 4; ++j) Ls[(tc * 4 + j) * 72 + r] = f2bf(vv[j]);
    }
    __syncthreads();
    const int KB = K >> 3;
    const int n = t >> 2;
    const int ks = t & 3;
    const int gn = bn + n;
    size_t base = ((size_t)(gn >> 4) * KB + ((bk + ks * 16) >> 3)) * 128 + (gn & 15) * 8;
    *(uint4*)(&dst[base])       = *(const uint4*)(&Ls[n * 72 + ks * 16]);
    *(uint4*)(&dst[base + 128]) = *(const uint4*)(&Ls[n * 72 + ks * 16 + 8]);
}

#define CVT_BLOCKS   3072                 // TSZ/4/256
#define PW1_BLOCKS   (12 * 36)            // Wqkv 64x64 tiles
#define PW2_BLOCKS   (12 * 12)            // Wout tiles

__global__ __launch_bounds__(256) void prep_kernel(
    const float* __restrict__ X, const float* __restrict__ Wqkv, const float* __restrict__ Wout,
    ushort_t* __restrict__ Ap, ushort_t* __restrict__ Wqp, ushort_t* __restrict__ Wop)
{
    __shared__ ushort_t Ls[64 * 72];
    const int b = blockIdx.x;
    const int t = threadIdx.x;
    if (b < CVT_BLOCKS) {
        int i = b * 256 + t;
        int row = i / (DIMM / 4);
        int k0 = (i - row * (DIMM / 4)) * 4;
        float4 v = *(const float4*)(&X[(size_t)row * DIMM + k0]);
        u16x4 p = { f2bf(v.x), f2bf(v.y), f2bf(v.z), f2bf(v.w) };
        size_t idx = ((size_t)(row >> 4) * (DIMM / 8) + (k0 >> 3)) * 128 + (row & 15) * 8 + (k0 & 7);
        *(u16x4*)(&Ap[idx]) = p;
    } else if (b < CVT_BLOCKS + PW1_BLOCKS) {
        int j = b - CVT_BLOCKS;
        pack_w_tile(Wqkv, Wqp, DIMM, NQKV, (j % 12) * 64, (j / 12) * 64, t, Ls);
    } else {
        int j = b - CVT_BLOCKS - PW1_BLOCKS;
        pack_w_tile(Wout, Wop, DIMM, DIMM, (j % 12) * 64, (j / 12) * 64, t, Ls);
    }
}

// ---------------- QKV GEMM, v3 (r13-proven): staged structure + T1 bijective XCD swizzle.
#define QKV_STAGE(buf, kt) do {                                          \
    gload_lds16(asrc0 + (kt) * 512, &As[buf][(w * 2)     * 512]);        \
    gload_lds16(asrc1 + (kt) * 512, &As[buf][(w * 2 + 1) * 512]);        \
    gload_lds16(bsrc0 + (kt) * 512, &Bs[buf][(w * 2)     * 512]);        \
    gload_lds16(bsrc1 + (kt) * 512, &Bs[buf][(w * 2 + 1) * 512]);        \
} while (0)

#define QKV_FRAGS(cur) \
    bf16x8 af[4], bfv[4];                                                \
    _Pragma("unroll")                                                    \
    for (int mi = 0; mi < 4; ++mi)                                       \
        af[mi] = *(const bf16x8*)(&As[cur][aoff + mi * 512 + lfr]);      \
    _Pragma("unroll")                                                    \
    for (int nj = 0; nj < 4; ++nj)                                       \
        bfv[nj] = *(const bf16x8*)(&Bs[cur][boff + nj * 512 + lfr]);

__global__ __launch_bounds__(256) void qkv_gemm_kernel(
    const ushort_t* __restrict__ Ap, const ushort_t* __restrict__ Bp,
    ushort_t* __restrict__ Qp, ushort_t* __restrict__ Kp, ushort_t* __restrict__ Vp)
{
    __shared__ ushort_t As[2][4096], Bs[2][4096];
    const int t = threadIdx.x;
    const int lane = t & 63;
    const int w = t >> 6;
    const int m16 = lane & 15;
    const int g = lane >> 4;
    const int wrow = (w >> 1) * 64;
    const int wcol = (w & 1) * 64;

    // T1 bijective XCD swizzle (576 = 8 x 72)
    const int d = blockIdx.x;
    const int sid = (d & 7) * 72 + (d >> 3);
    const int bx = sid % 18;
    const int by = sid / 18;

    const int bm = by * 128;
    const int bn = bx * 128;
    const int amb = (bm + wrow) >> 4;
    const int bnb = (bn + wcol) >> 4;
    const int bm16 = bm >> 4;
    const int bn16 = bn >> 4;
    const int KB = DIMM / 8;  // 96
    const int which = bn / DIMM;  // 0=Q 1=K 2=V

    const ushort_t* asrc0 = Ap + ((size_t)(bm16 + w * 2)     * KB) * 128 + lane * 8;
    const ushort_t* asrc1 = Ap + ((size_t)(bm16 + w * 2 + 1) * KB) * 128 + lane * 8;
    const ushort_t* bsrc0 = Bp + ((size_t)(bn16 + w * 2)     * KB) * 128 + lane * 8;
    const ushort_t* bsrc1 = Bp + ((size_t)(bn16 + w * 2 + 1) * KB) * 128 + lane * 8;
    const int aoff = (w >> 1) * 2048;   // this wave's 4 A-chunks
    const int boff = (w & 1) * 2048;    // this wave's 4 B-chunks
    const int lfr = g * 128 + m16 * 8;  // fragment lane offset within a chunk

    f32x4 acc[4][4];
#pragma unroll
    for (int i = 0; i < 4; ++i)
#pragma unroll
        for (int j = 0; j < 4; ++j) acc[i][j] = zero4();

    QKV_STAGE(0, 0);
    __syncthreads();   // (compiler drains vmcnt before barrier) tile 0 landed

    if (which < 2) {
        // transposed product: acc rows = out-channel, cols = seq
        for (int kt = 0; kt < 24; ++kt) {
            const int cur = kt & 1;
            if (kt + 1 < 24) QKV_STAGE(cur ^ 1, kt + 1);
            QKV_FRAGS(cur);
#pragma unroll
            for (int mi = 0; mi < 4; ++mi)
#pragma unroll
                for (int nj = 0; nj < 4; ++nj)
                    acc[mi][nj] = __builtin_amdgcn_mfma_f32_16x16x32_bf16(bfv[nj], af[mi], acc[mi][nj], 0, 0, 0);
            __syncthreads();   // prefetch landed + everyone done reading cur
        }
        ushort_t* dst = (which == 0) ? Qp : Kp;
        const float scale = (which == 0) ? LOG2E : 1.0f;
        const int cb = bn - which * DIMM + wcol;
        const int h = cb >> 6;
        const int ghi = g >> 1, glo = g & 1;
#pragma unroll
        for (int mi = 0; mi < 4; ++mi) {
            int sblk = amb + mi;
#pragma unroll
            for (int nj = 0; nj < 4; ++nj) {
                size_t idx = (((size_t)h * 256 + sblk) * 8 + nj * 2 + ghi) * 128 + m16 * 8 + glo * 4;
                u16x4 pk = { f2bf(acc[mi][nj][0] * scale), f2bf(acc[mi][nj][1] * scale),
                             f2bf(acc[mi][nj][2] * scale), f2bf(acc[mi][nj][3] * scale) };
                *(u16x4*)(&dst[idx]) = pk;
            }
        }
    } else {
        // original orientation: acc rows = key, cols = d
        for (int kt = 0; kt < 24; ++kt) {
            const int cur = kt & 1;
            if (kt + 1 < 24) QKV_STAGE(cur ^ 1, kt + 1);
            QKV_FRAGS(cur);
#pragma unroll
            for (int mi = 0; mi < 4; ++mi)
#pragma unroll
                for (int nj = 0; nj < 4; ++nj)
                    acc[mi][nj] = __builtin_amdgcn_mfma_f32_16x16x32_bf16(af[mi], bfv[nj], acc[mi][nj], 0, 0, 0);
            __syncthreads();
        }
        const int cb = bn - 2 * DIMM + wcol;
        const int h = cb >> 6;
        const int ghi = g >> 1, glo = g & 1;
        const int kb8 = (bm + wrow) >> 3;
#pragma unroll
        for (int mi = 0; mi < 4; ++mi) {
#pragma unroll
            for (int nj = 0; nj < 4; ++nj) {
                size_t idx = (((size_t)h * 512 + kb8 + mi * 2 + ghi) * 4 + nj) * 128 + m16 * 8 + glo * 4;
                u16x4 pk = { f2bf(acc[mi][nj][0]), f2bf(acc[mi][nj][1]),
                             f2bf(acc[mi][nj][2]), f2bf(acc[mi][nj][3]) };
                *(u16x4*)(&Vp[idx]) = pk;
            }
        }
    }
}

// ---------------- Flash attention, v12: r10 body + bf16 Opart (r14) + l-via-MFMA (r1-
// proven mechanism). lacc VALU adds (32/step) and the epilogue shuffle-reduce move to
// the matrix pipe: lfrag[mi] = mfma(pf, ones, lfrag[mi]) gives D[i,j] = sum_k P[i,k]
// replicated over m16 columns; row i = g*4+r matches the L epilogue directly (r1:
// VALUBusy 34.4->29.7, passed). VALU is the busier pipe (37-38% vs MFMA 34%), so the
// shift shortens the per-wave serial chain.
#define ATTN_LOADK(dst, ptr) do {                          \
    dst[0][0] = *(const bf16x8*)(ptr);                     \
    dst[0][1] = *(const bf16x8*)((ptr) + 512);             \
    dst[1][0] = *(const bf16x8*)((ptr) + 1024);            \
    dst[1][1] = *(const bf16x8*)((ptr) + 1536);            \
} while (0)

#define ATTN_LOADV(dst, ptr) do {                          \
    dst[0] = *(const bf16x8*)(ptr);                        \
    dst[1] = *(const bf16x8*)((ptr) + 128);                \
    dst[2] = *(const bf16x8*)((ptr) + 256);                \
    dst[3] = *(const bf16x8*)((ptr) + 384);                \
} while (0)

__global__ __launch_bounds__(128, 3) void attn_kernel(
    const ushort_t* __restrict__ Qp, const ushort_t* __restrict__ Kp,
    const ushort_t* __restrict__ Vp, ushort_t* __restrict__ Opart, float* __restrict__ Lpart,
    int niter)
{
    __shared__ ushort_t Ps[2][64 * 40];
    const int t = threadIdx.x;
    const int lane = t & 63;
    const int w = t >> 6;           // 0..1
    const int m16 = lane & 15;
    const int g = lane >> 4;

    // T1 bijective XCD swizzle (r10-proven): XCD c owns a contiguous chunk of the
    // (qb, h, quarter) ordering = 6 heads x one sequence-quarter (3MB <= L2).
    const int cpx = gridDim.x >> 3;                 // 192 (nsplit=4) or 96 (nsplit=2)
    const int d = blockIdx.x;
    const int sid = (d & 7) * cpx + (d >> 3);
    const int qbi  = sid & 31;                      // NSEQ/128 = 32 q-blocks
    const int rem  = sid >> 5;
    const int h    = rem % HEADS;
    const int half = rem / HEADS;                   // sequence quarter (nsplit index)

    const int qb = qbi * 128 + w * 64;   // 64 q-rows per wave
    const int qblk0 = qb >> 4;
    const int kblk0 = half * niter * 4;
    const int vblk0 = half * niter * 8;

    bf16x8 qf[4][2];
#pragma unroll
    for (int mi = 0; mi < 4; ++mi)
#pragma unroll
        for (int kd = 0; kd < 2; ++kd)
            qf[mi][kd] = *(const bf16x8*)(&Qp[(((size_t)h * 256 + qblk0 + mi) * 8 + kd * 4 + g) * 128 + m16 * 8]);

    const ushort_t* kp = Kp + ((size_t)h * 256 + kblk0) * 1024 + g * 128 + m16 * 8;
    const ushort_t* vp = Vp + ((size_t)h * 512 + vblk0) * 512 + g * 512 + m16 * 8;

    bf16x8 onesf;
#pragma unroll
    for (int i = 0; i < 8; ++i) onesf[i] = (__bf16)1.0f;

    f32x4 oacc[4][4];
#pragma unroll
    for (int mi = 0; mi < 4; ++mi)
#pragma unroll
        for (int dj = 0; dj < 4; ++dj) oacc[mi][dj] = zero4();
    f32x4 lfrag[4] = {zero4(), zero4(), zero4(), zero4()};

    const int nsteps = niter * 2;   // 32-key steps
    for (int s = 0; s < nsteps; ++s) {
        bf16x8 kf[2][2], vf[4];
        ATTN_LOADK(kf, kp); kp += 2048;
        ATTN_LOADV(vf, vp); vp += 2048;
        asm volatile("" ::: "memory");   // pin load issue at step top; waitcnt lands at use
#pragma unroll
        for (int mi = 0; mi < 4; ++mi) {
            // S^T: rows=keys (nj*16+g*4+r), cols=q (mi*16+m16); p = 2^s (log2e baked into Q)
#pragma unroll
            for (int nj = 0; nj < 2; ++nj) {
                f32x4 st = zero4();
                st = __builtin_amdgcn_mfma_f32_16x16x32_bf16(kf[nj][0], qf[mi][0], st, 0, 0, 0);
                st = __builtin_amdgcn_mfma_f32_16x16x32_bf16(kf[nj][1], qf[mi][1], st, 0, 0, 0);
                f32x4 p;
#pragma unroll
                for (int r = 0; r < 4; ++r) p[r] = EXP2(st[r]);
                bf16x4 pk = { (__bf16)p[0], (__bf16)p[1], (__bf16)p[2], (__bf16)p[3] };
                *(bf16x4*)(&Ps[w][(mi * 16 + m16) * 40 + nj * 16 + g * 4]) = pk;
            }
            // P A-frag (wave-private LDS; in-order DS ops, no barrier)
            bf16x8 pf = *(const bf16x8*)(&Ps[w][(mi * 16 + m16) * 40 + g * 8]);
            // l = P @ ones on the matrix pipe (replaces 32 VALU adds/step + epilogue shuffles)
            lfrag[mi] = __builtin_amdgcn_mfma_f32_16x16x32_bf16(pf, onesf, lfrag[mi], 0, 0, 0);
#pragma unroll
            for (int dj = 0; dj < 4; ++dj)
                oacc[mi][dj] = __builtin_amdgcn_mfma_f32_16x16x32_bf16(pf, vf[dj], oacc[mi][dj], 0, 0, 0);
        }
    }

    ushort_t* Oph = Opart + (size_t)half * NSEQ * DIMM;
    float* Lph = Lpart + (size_t)half * HEADS * NSEQ + (size_t)h * NSEQ;
    // l = P @ ones: D[row=q_local=g*4+r] replicated over m16 columns
    if (m16 == 0) {
#pragma unroll
        for (int mi = 0; mi < 4; ++mi)
#pragma unroll
            for (int r = 0; r < 4; ++r)
                Lph[qb + mi * 16 + g * 4 + r] = lfrag[mi][r];
    }
#pragma unroll
    for (int mi = 0; mi < 4; ++mi) {
#pragma unroll
        for (int r = 0; r < 4; ++r) {
            int row = qb + mi * 16 + g * 4 + r;
#pragma unroll
            for (int dj = 0; dj < 4; ++dj)
                Oph[(size_t)row * DIMM + h * 64 + dj * 16 + m16] = f2bf(oacc[mi][dj][r]);
        }
    }
}

// ---------------- Merge nsplit bf16 partials -> Xap frag-major bf16
__global__ __launch_bounds__(256) void merge_kernel(
    const ushort_t* __restrict__ Opart, const float* __restrict__ Lpart,
    ushort_t* __restrict__ Xap, int nsplit)
{
    int i = blockIdx.x * 256 + threadIdx.x;
    int row = i / (DIMM / 4);
    int col0 = (i - row * (DIMM / 4)) * 4;
    int h = col0 >> 6;
    float l = 0.f;
    f32x4 o = zero4();
    for (int s = 0; s < nsplit; ++s) {
        l += Lpart[(size_t)s * HEADS * NSEQ + (size_t)h * NSEQ + row];
        u16x4 ov = *(const u16x4*)(&Opart[(size_t)s * NSEQ * DIMM + (size_t)row * DIMM + col0]);
#pragma unroll
        for (int j = 0; j < 4; ++j) o[j] += bf2f(ov[j]);
    }
    float inv = 1.0f / l;
    u16x4 p = { f2bf(o[0] * inv), f2bf(o[1] * inv), f2bf(o[2] * inv), f2bf(o[3] * inv) };
    size_t idx = ((size_t)(row >> 4) * (DIMM / 8) + (col0 >> 3)) * 128 + (row & 15) * 8 + (col0 & 7);
    *(u16x4*)(&Xap[idx]) = p;
}

// ---------------- Output projection: r11-proven version (32x64 wave tiles, 1-wave
// blocks, 1536 blocks of high TLP; r12 proved staged-LDS loses here).
__global__ __launch_bounds__(64, 4) void out_gemm_kernel(
    const ushort_t* __restrict__ Ap, const ushort_t* __restrict__ Bp,
    const float* __restrict__ bias, float* __restrict__ out)
{
    const int lane = threadIdx.x & 63;
    const int m16 = lane & 15;
    const int g = lane >> 4;
    const int bm = blockIdx.y * 32;
    const int bn = blockIdx.x * 64;
    const int amb = bm >> 4;
    const int bnb = bn >> 4;
    const int KB = DIMM / 8;  // 96

    f32x4 acc[2][4];
#pragma unroll
    for (int i = 0; i < 2; ++i)
#pragma unroll
        for (int j = 0; j < 4; ++j) acc[i][j] = zero4();

#pragma unroll 2
    for (int kt = 0; kt < 24; ++kt) {
        bf16x8 af[2], bfv[4];
#pragma unroll
        for (int mi = 0; mi < 2; ++mi)
            af[mi] = *(const bf16x8*)(&Ap[((size_t)(amb + mi) * KB + kt * 4 + g) * 128 + m16 * 8]);
#pragma unroll
        for (int nj = 0; nj < 4; ++nj)
            bfv[nj] = *(const bf16x8*)(&Bp[((size_t)(bnb + nj) * KB + kt * 4 + g) * 128 + m16 * 8]);
#pragma unroll
        for (int mi = 0; mi < 2; ++mi)
#pragma unroll
            for (int nj = 0; nj < 4; ++nj)
                acc[mi][nj] = __builtin_amdgcn_mfma_f32_16x16x32_bf16(af[mi], bfv[nj], acc[mi][nj], 0, 0, 0);
    }
#pragma unroll
    for (int mi = 0; mi < 2; ++mi) {
#pragma unroll
        for (int nj = 0; nj < 4; ++nj) {
            int col = bn + nj * 16 + m16;
            float bv = bias[col];
#pragma unroll
            for (int r = 0; r < 4; ++r) {
                int row = bm + mi * 16 + g * 4 + r;
                out[(size_t)row * DIMM + col] = acc[mi][nj][r] + bv;
            }
        }
    }
}

extern "C" void kernel_launch(void* const* d_in, const int* in_sizes, int n_in,
                              void* d_out, int out_size, void* d_ws, size_t ws_size,
                              hipStream_t stream) {
    (void)in_sizes; (void)n_in; (void)out_size;
    const float* X    = (const float*)d_in[0];
    const float* Wqkv = (const float*)d_in[1];
    const float* Wout = (const float*)d_in[2];
    const float* bout = (const float*)d_in[3];
    float* out = (float*)d_out;

    const size_t TSZ = (size_t)NSEQ * DIMM;  // 3145728
    const size_t fixed = TSZ * 2 * 5 + (size_t)NQKV * DIMM * 2 + (size_t)DIMM * DIMM * 2;
    const size_t per_split = TSZ * 2 + (size_t)HEADS * NSEQ * 4;   // bf16 Opart + f32 Lpart
    const int nsplit = (ws_size >= fixed + 4 * per_split) ? 4 : 2;

    unsigned char* p = (unsigned char*)d_ws;
    ushort_t* Ap  = (ushort_t*)p; p += TSZ * 2;
    ushort_t* Wqp = (ushort_t*)p; p += (size_t)NQKV * DIMM * 2;
    ushort_t* Wop = (ushort_t*)p; p += (size_t)DIMM * DIMM * 2;
    ushort_t* Qp  = (ushort_t*)p; p += TSZ * 2;
    ushort_t* Kp  = (ushort_t*)p; p += TSZ * 2;
    ushort_t* Vp  = (ushort_t*)p; p += TSZ * 2;
    ushort_t* Xap = (ushort_t*)p; p += TSZ * 2;
    ushort_t* Opart = (ushort_t*)p; p += (size_t)nsplit * TSZ * 2;
    float* Lpart  = (float*)p;

    const int niter = (NSEQ / 64) / nsplit;

    prep_kernel<<<CVT_BLOCKS + PW1_BLOCKS + PW2_BLOCKS, 256, 0, stream>>>(X, Wqkv, Wout, Ap, Wqp, Wop);
    qkv_gemm_kernel<<<dim3(576), 256, 0, stream>>>(Ap, Wqp, Qp, Kp, Vp);
    attn_kernel<<<dim3((NSEQ / 128) * HEADS * nsplit), 128, 0, stream>>>(Qp, Kp, Vp, Opart, Lpart, niter);
    merge_kernel<<<TSZ / 4 / 256, 256, 0, stream>>>(Opart, Lpart, Xap, nsplit);
    out_gemm_kernel<<<dim3(DIMM / 64, NSEQ / 32), 64, 0, stream>>>(Xap, Wop, bout, out);
}

// Round 16
// 185.060 us; speedup vs baseline: 1.0721x; 1.0010x over previous
//
#include <hip/hip_runtime.h>

typedef unsigned short ushort_t;
typedef unsigned int uint_t;
typedef __bf16 bf16x8 __attribute__((ext_vector_type(8)));
typedef __bf16 bf16x4 __attribute__((ext_vector_type(4)));
typedef float f32x4 __attribute__((ext_vector_type(4)));
typedef ushort_t u16x4 __attribute__((ext_vector_type(4)));

#define NSEQ 4096
#define DIMM 768
#define NQKV 2304
#define HEADS 12
#define LOG2E 1.4426950408889634f

#if __has_builtin(__builtin_amdgcn_exp2f)
#define EXP2(x) __builtin_amdgcn_exp2f(x)
#else
#define EXP2(x) exp2f(x)
#endif

// Fragment-major packing: element (row,k) lives at
//   ((row>>4)*KB + (k>>3))*128 + (row&15)*8 + (k&7)      [KB = K/8]

__device__ __forceinline__ ushort_t f2bf(float f) {
    uint_t u = __float_as_uint(f);
    u = u + 0x7fffu + ((u >> 16) & 1u);
    return (ushort_t)(u >> 16);
}
__device__ __forceinline__ float bf2f(ushort_t v) {
    return __uint_as_float(((uint_t)v) << 16);
}
__device__ __forceinline__ f32x4 zero4() {
    f32x4 v = {0.f, 0.f, 0.f, 0.f};
    return v;
}

// Async global->LDS DMA, 16B per lane. Dest rule (HW): wave-uniform LDS base + lane*16.
// No destination VGPR => the scheduler cannot sink it to a use (rounds 1-3/6/9 failure mode).
__device__ __forceinline__ void gload_lds16(const ushort_t* g, ushort_t* l) {
    __builtin_amdgcn_global_load_lds(
        (const __attribute__((address_space(1))) void*)g,
        (__attribute__((address_space(3))) void*)l, 16, 0, 0);
}

// ---------------- fused prep: X cvt+pack, Wqkv pack, Wout pack (one launch)
__device__ __forceinline__ void pack_w_tile(const float* __restrict__ src,
                                            ushort_t* __restrict__ dst,
                                            int K, int N, int bk, int bn, int t,
                                            ushort_t* Ls) {
    const int tr = t >> 4, tc = t & 15;
#pragma unroll
    for (int i = 0; i < 4; ++i) {
        int r = tr + 16 * i;  // k within tile
        float4 v = *(const float4*)(&src[(size_t)(bk + r) * N + bn + tc * 4]);
        const float* vv = (const float*)&v;
#pragma unroll
        for (int j = 0; j < 4; ++j) Ls[(tc * 4 + j) * 72 + r] = f2bf(vv[j]);
    }
    __syncthreads();
    const int KB = K >> 3;
    const int n = t >> 2;
    const int ks = t & 3;
    const int gn = bn + n;
    size_t base = ((size_t)(gn >> 4) * KB + ((bk + ks * 16) >> 3)) * 128 + (gn & 15) * 8;
    *(uint4*)(&dst[base])       = *(const uint4*)(&Ls[n * 72 + ks * 16]);
    *(uint4*)(&dst[base + 128]) = *(const uint4*)(&Ls[n * 72 + ks * 16 + 8]);
}

#define CVT_BLOCKS   3072                 // TSZ/4/256
#define PW1_BLOCKS   (12 * 36)            // Wqkv 64x64 tiles
#define PW2_BLOCKS   (12 * 12)            // Wout tiles

__global__ __launch_bounds__(256) void prep_kernel(
    const float* __restrict__ X, const float* __restrict__ Wqkv, const float* __restrict__ Wout,
    ushort_t* __restrict__ Ap, ushort_t* __restrict__ Wqp, ushort_t* __restrict__ Wop)
{
    __shared__ ushort_t Ls[64 * 72];
    const int b = blockIdx.x;
    const int t = threadIdx.x;
    if (b < CVT_BLOCKS) {
        int i = b * 256 + t;
        int row = i / (DIMM / 4);
        int k0 = (i - row * (DIMM / 4)) * 4;
        float4 v = *(const float4*)(&X[(size_t)row * DIMM + k0]);
        u16x4 p = { f2bf(v.x), f2bf(v.y), f2bf(v.z), f2bf(v.w) };
        size_t idx = ((size_t)(row >> 4) * (DIMM / 8) + (k0 >> 3)) * 128 + (row & 15) * 8 + (k0 & 7);
        *(u16x4*)(&Ap[idx]) = p;
    } else if (b < CVT_BLOCKS + PW1_BLOCKS) {
        int j = b - CVT_BLOCKS;
        pack_w_tile(Wqkv, Wqp, DIMM, NQKV, (j % 12) * 64, (j / 12) * 64, t, Ls);
    } else {
        int j = b - CVT_BLOCKS - PW1_BLOCKS;
        pack_w_tile(Wout, Wop, DIMM, DIMM, (j % 12) * 64, (j / 12) * 64, t, Ls);
    }
}

// ---------------- QKV GEMM, v3 (r13-proven): staged structure + T1 bijective XCD swizzle.
#define QKV_STAGE(buf, kt) do {                                          \
    gload_lds16(asrc0 + (kt) * 512, &As[buf][(w * 2)     * 512]);        \
    gload_lds16(asrc1 + (kt) * 512, &As[buf][(w * 2 + 1) * 512]);        \
    gload_lds16(bsrc0 + (kt) * 512, &Bs[buf][(w * 2)     * 512]);        \
    gload_lds16(bsrc1 + (kt) * 512, &Bs[buf][(w * 2 + 1) * 512]);        \
} while (0)

#define QKV_FRAGS(cur) \
    bf16x8 af[4], bfv[4];                                                \
    _Pragma("unroll")                                                    \
    for (int mi = 0; mi < 4; ++mi)                                       \
        af[mi] = *(const bf16x8*)(&As[cur][aoff + mi * 512 + lfr]);      \
    _Pragma("unroll")                                                    \
    for (int nj = 0; nj < 4; ++nj)                                       \
        bfv[nj] = *(const bf16x8*)(&Bs[cur][boff + nj * 512 + lfr]);

__global__ __launch_bounds__(256) void qkv_gemm_kernel(
    const ushort_t* __restrict__ Ap, const ushort_t* __restrict__ Bp,
    ushort_t* __restrict__ Qp, ushort_t* __restrict__ Kp, ushort_t* __restrict__ Vp)
{
    __shared__ ushort_t As[2][4096], Bs[2][4096];
    const int t = threadIdx.x;
    const int lane = t & 63;
    const int w = t >> 6;
    const int m16 = lane & 15;
    const int g = lane >> 4;
    const int wrow = (w >> 1) * 64;
    const int wcol = (w & 1) * 64;

    // T1 bijective XCD swizzle (576 = 8 x 72)
    const int d = blockIdx.x;
    const int sid = (d & 7) * 72 + (d >> 3);
    const int bx = sid % 18;
    const int by = sid / 18;

    const int bm = by * 128;
    const int bn = bx * 128;
    const int amb = (bm + wrow) >> 4;
    const int bnb = (bn + wcol) >> 4;
    const int bm16 = bm >> 4;
    const int bn16 = bn >> 4;
    const int KB = DIMM / 8;  // 96
    const int which = bn / DIMM;  // 0=Q 1=K 2=V

    const ushort_t* asrc0 = Ap + ((size_t)(bm16 + w * 2)     * KB) * 128 + lane * 8;
    const ushort_t* asrc1 = Ap + ((size_t)(bm16 + w * 2 + 1) * KB) * 128 + lane * 8;
    const ushort_t* bsrc0 = Bp + ((size_t)(bn16 + w * 2)     * KB) * 128 + lane * 8;
    const ushort_t* bsrc1 = Bp + ((size_t)(bn16 + w * 2 + 1) * KB) * 128 + lane * 8;
    const int aoff = (w >> 1) * 2048;   // this wave's 4 A-chunks
    const int boff = (w & 1) * 2048;    // this wave's 4 B-chunks
    const int lfr = g * 128 + m16 * 8;  // fragment lane offset within a chunk

    f32x4 acc[4][4];
#pragma unroll
    for (int i = 0; i < 4; ++i)
#pragma unroll
        for (int j = 0; j < 4; ++j) acc[i][j] = zero4();

    QKV_STAGE(0, 0);
    __syncthreads();   // (compiler drains vmcnt before barrier) tile 0 landed

    if (which < 2) {
        // transposed product: acc rows = out-channel, cols = seq
        for (int kt = 0; kt < 24; ++kt) {
            const int cur = kt & 1;
            if (kt + 1 < 24) QKV_STAGE(cur ^ 1, kt + 1);
            QKV_FRAGS(cur);
#pragma unroll
            for (int mi = 0; mi < 4; ++mi)
#pragma unroll
                for (int nj = 0; nj < 4; ++nj)
                    acc[mi][nj] = __builtin_amdgcn_mfma_f32_16x16x32_bf16(bfv[nj], af[mi], acc[mi][nj], 0, 0, 0);
            __syncthreads();   // prefetch landed + everyone done reading cur
        }
        ushort_t* dst = (which == 0) ? Qp : Kp;
        const float scale = (which == 0) ? LOG2E : 1.0f;
        const int cb = bn - which * DIMM + wcol;
        const int h = cb >> 6;
        const int ghi = g >> 1, glo = g & 1;
#pragma unroll
        for (int mi = 0; mi < 4; ++mi) {
            int sblk = amb + mi;
#pragma unroll
            for (int nj = 0; nj < 4; ++nj) {
                size_t idx = (((size_t)h * 256 + sblk) * 8 + nj * 2 + ghi) * 128 + m16 * 8 + glo * 4;
                u16x4 pk = { f2bf(acc[mi][nj][0] * scale), f2bf(acc[mi][nj][1] * scale),
                             f2bf(acc[mi][nj][2] * scale), f2bf(acc[mi][nj][3] * scale) };
                *(u16x4*)(&dst[idx]) = pk;
            }
        }
    } else {
        // original orientation: acc rows = key, cols = d
        for (int kt = 0; kt < 24; ++kt) {
            const int cur = kt & 1;
            if (kt + 1 < 24) QKV_STAGE(cur ^ 1, kt + 1);
            QKV_FRAGS(cur);
#pragma unroll
            for (int mi = 0; mi < 4; ++mi)
#pragma unroll
                for (int nj = 0; nj < 4; ++nj)
                    acc[mi][nj] = __builtin_amdgcn_mfma_f32_16x16x32_bf16(af[mi], bfv[nj], acc[mi][nj], 0, 0, 0);
            __syncthreads();
        }
        const int cb = bn - 2 * DIMM + wcol;
        const int h = cb >> 6;
        const int ghi = g >> 1, glo = g & 1;
        const int kb8 = (bm + wrow) >> 3;
#pragma unroll
        for (int mi = 0; mi < 4; ++mi) {
#pragma unroll
            for (int nj = 0; nj < 4; ++nj) {
                size_t idx = (((size_t)h * 512 + kb8 + mi * 2 + ghi) * 4 + nj) * 128 + m16 * 8 + glo * 4;
                u16x4 pk = { f2bf(acc[mi][nj][0]), f2bf(acc[mi][nj][1]),
                             f2bf(acc[mi][nj][2]), f2bf(acc[mi][nj][3]) };
                *(u16x4*)(&Vp[idx]) = pk;
            }
        }
    }
}

// ---------------- Flash attention, v13: r15 body (l-via-MFMA, bf16 Opart, XCD swizzle)
// + XOR-swizzled Ps (G4). The 40-ushort row stride had dword-stride 20, gcd(20,32)=4 ->
// only 8 distinct banks over 16 m16 lanes = 4.0 measured extra cycles per DS op
// (SQ_LDS_BANK_CONFLICT/ops = 4718592/1179648). Any 16B-multiple stride has gcd>=4, so
// padding can't fix it; instead rows are 64 ushorts (128B) and the sub-row offset is
// XORed with sw = (m16&7)<<3 (same involution on write and read; stays within the row;
// preserves 8B write / 16B read alignment; read slot g covers exactly write chunks
// nj=g>>1, g' in {2(g&1), 2(g&1)+1} as before). Arithmetic bit-identical.
#define ATTN_LOADK(dst, ptr) do {                          \
    dst[0][0] = *(const bf16x8*)(ptr);                     \
    dst[0][1] = *(const bf16x8*)((ptr) + 512);             \
    dst[1][0] = *(const bf16x8*)((ptr) + 1024);            \
    dst[1][1] = *(const bf16x8*)((ptr) + 1536);            \
} while (0)

#define ATTN_LOADV(dst, ptr) do {                          \
    dst[0] = *(const bf16x8*)(ptr);                        \
    dst[1] = *(const bf16x8*)((ptr) + 128);                \
    dst[2] = *(const bf16x8*)((ptr) + 256);                \
    dst[3] = *(const bf16x8*)((ptr) + 384);                \
} while (0)

__global__ __launch_bounds__(128, 3) void attn_kernel(
    const ushort_t* __restrict__ Qp, const ushort_t* __restrict__ Kp,
    const ushort_t* __restrict__ Vp, ushort_t* __restrict__ Opart, float* __restrict__ Lpart,
    int niter)
{
    __shared__ ushort_t Ps[2][64 * 64];   // 128B rows, XOR-swizzled sub-row offsets
    const int t = threadIdx.x;
    const int lane = t & 63;
    const int w = t >> 6;           // 0..1
    const int m16 = lane & 15;
    const int g = lane >> 4;
    const int sw = (m16 & 7) << 3;  // XOR key ((row&7)<<3 in ushorts; row&7 == m16&7)

    // T1 bijective XCD swizzle (r10-proven): XCD c owns a contiguous chunk of the
    // (qb, h, quarter) ordering = 6 heads x one sequence-quarter (3MB <= L2).
    const int cpx = gridDim.x >> 3;                 // 192 (nsplit=4) or 96 (nsplit=2)
    const int d = blockIdx.x;
    const int sid = (d & 7) * cpx + (d >> 3);
    const int qbi  = sid & 31;                      // NSEQ/128 = 32 q-blocks
    const int rem  = sid >> 5;
    const int h    = rem % HEADS;
    const int half = rem / HEADS;                   // sequence quarter (nsplit index)

    const int qb = qbi * 128 + w * 64;   // 64 q-rows per wave
    const int qblk0 = qb >> 4;
    const int kblk0 = half * niter * 4;
    const int vblk0 = half * niter * 8;

    bf16x8 qf[4][2];
#pragma unroll
    for (int mi = 0; mi < 4; ++mi)
#pragma unroll
        for (int kd = 0; kd < 2; ++kd)
            qf[mi][kd] = *(const bf16x8*)(&Qp[(((size_t)h * 256 + qblk0 + mi) * 8 + kd * 4 + g) * 128 + m16 * 8]);

    const ushort_t* kp = Kp + ((size_t)h * 256 + kblk0) * 1024 + g * 128 + m16 * 8;
    const ushort_t* vp = Vp + ((size_t)h * 512 + vblk0) * 512 + g * 512 + m16 * 8;

    bf16x8 onesf;
#pragma unroll
    for (int i = 0; i < 8; ++i) onesf[i] = (__bf16)1.0f;

    f32x4 oacc[4][4];
#pragma unroll
    for (int mi = 0; mi < 4; ++mi)
#pragma unroll
        for (int dj = 0; dj < 4; ++dj) oacc[mi][dj] = zero4();
    f32x4 lfrag[4] = {zero4(), zero4(), zero4(), zero4()};

    const int nsteps = niter * 2;   // 32-key steps
    for (int s = 0; s < nsteps; ++s) {
        bf16x8 kf[2][2], vf[4];
        ATTN_LOADK(kf, kp); kp += 2048;
        ATTN_LOADV(vf, vp); vp += 2048;
        asm volatile("" ::: "memory");   // pin load issue at step top; waitcnt lands at use
#pragma unroll
        for (int mi = 0; mi < 4; ++mi) {
            // S^T: rows=keys (nj*16+g*4+r), cols=q (mi*16+m16); p = 2^s (log2e baked into Q)
#pragma unroll
            for (int nj = 0; nj < 2; ++nj) {
                f32x4 st = zero4();
                st = __builtin_amdgcn_mfma_f32_16x16x32_bf16(kf[nj][0], qf[mi][0], st, 0, 0, 0);
                st = __builtin_amdgcn_mfma_f32_16x16x32_bf16(kf[nj][1], qf[mi][1], st, 0, 0, 0);
                f32x4 p;
#pragma unroll
                for (int r = 0; r < 4; ++r) p[r] = EXP2(st[r]);
                bf16x4 pk = { (__bf16)p[0], (__bf16)p[1], (__bf16)p[2], (__bf16)p[3] };
                *(bf16x4*)(&Ps[w][(mi * 16 + m16) * 64 + ((nj * 16 + g * 4) ^ sw)]) = pk;
            }
            // P A-frag (wave-private LDS; in-order DS ops, no barrier)
            bf16x8 pf = *(const bf16x8*)(&Ps[w][(mi * 16 + m16) * 64 + ((g * 8) ^ sw)]);
            // l = P @ ones on the matrix pipe (r15-proven: replaces 32 VALU adds/step)
            lfrag[mi] = __builtin_amdgcn_mfma_f32_16x16x32_bf16(pf, onesf, lfrag[mi], 0, 0, 0);
#pragma unroll
            for (int dj = 0; dj < 4; ++dj)
                oacc[mi][dj] = __builtin_amdgcn_mfma_f32_16x16x32_bf16(pf, vf[dj], oacc[mi][dj], 0, 0, 0);
        }
    }

    ushort_t* Oph = Opart + (size_t)half * NSEQ * DIMM;
    float* Lph = Lpart + (size_t)half * HEADS * NSEQ + (size_t)h * NSEQ;
    // l = P @ ones: D[row=q_local=g*4+r] replicated over m16 columns
    if (m16 == 0) {
#pragma unroll
        for (int mi = 0; mi < 4; ++mi)
#pragma unroll
            for (int r = 0; r < 4; ++r)
                Lph[qb + mi * 16 + g * 4 + r] = lfrag[mi][r];
    }
#pragma unroll
    for (int mi = 0; mi < 4; ++mi) {
#pragma unroll
        for (int r = 0; r < 4; ++r) {
            int row = qb + mi * 16 + g * 4 + r;
#pragma unroll
            for (int dj = 0; dj < 4; ++dj)
                Oph[(size_t)row * DIMM + h * 64 + dj * 16 + m16] = f2bf(oacc[mi][dj][r]);
        }
    }
}

// ---------------- Merge nsplit bf16 partials -> Xap frag-major bf16
__global__ __launch_bounds__(256) void merge_kernel(
    const ushort_t* __restrict__ Opart, const float* __restrict__ Lpart,
    ushort_t* __restrict__ Xap, int nsplit)
{
    int i = blockIdx.x * 256 + threadIdx.x;
    int row = i / (DIMM / 4);
    int col0 = (i - row * (DIMM / 4)) * 4;
    int h = col0 >> 6;
    float l = 0.f;
    f32x4 o = zero4();
    for (int s = 0; s < nsplit; ++s) {
        l += Lpart[(size_t)s * HEADS * NSEQ + (size_t)h * NSEQ + row];
        u16x4 ov = *(const u16x4*)(&Opart[(size_t)s * NSEQ * DIMM + (size_t)row * DIMM + col0]);
#pragma unroll
        for (int j = 0; j < 4; ++j) o[j] += bf2f(ov[j]);
    }
    float inv = 1.0f / l;
    u16x4 p = { f2bf(o[0] * inv), f2bf(o[1] * inv), f2bf(o[2] * inv), f2bf(o[3] * inv) };
    size_t idx = ((size_t)(row >> 4) * (DIMM / 8) + (col0 >> 3)) * 128 + (row & 15) * 8 + (col0 & 7);
    *(u16x4*)(&Xap[idx]) = p;
}

// ---------------- Output projection: r11-proven version (32x64 wave tiles, 1-wave
// blocks, 1536 blocks of high TLP; r12 proved staged-LDS loses here).
__global__ __launch_bounds__(64, 4) void out_gemm_kernel(
    const ushort_t* __restrict__ Ap, const ushort_t* __restrict__ Bp,
    const float* __restrict__ bias, float* __restrict__ out)
{
    const int lane = threadIdx.x & 63;
    const int m16 = lane & 15;
    const int g = lane >> 4;
    const int bm = blockIdx.y * 32;
    const int bn = blockIdx.x * 64;
    const int amb = bm >> 4;
    const int bnb = bn >> 4;
    const int KB = DIMM / 8;  // 96

    f32x4 acc[2][4];
#pragma unroll
    for (int i = 0; i < 2; ++i)
#pragma unroll
        for (int j = 0; j < 4; ++j) acc[i][j] = zero4();

#pragma unroll 2
    for (int kt = 0; kt < 24; ++kt) {
        bf16x8 af[2], bfv[4];
#pragma unroll
        for (int mi = 0; mi < 2; ++mi)
            af[mi] = *(const bf16x8*)(&Ap[((size_t)(amb + mi) * KB + kt * 4 + g) * 128 + m16 * 8]);
#pragma unroll
        for (int nj = 0; nj < 4; ++nj)
            bfv[nj] = *(const bf16x8*)(&Bp[((size_t)(bnb + nj) * KB + kt * 4 + g) * 128 + m16 * 8]);
#pragma unroll
        for (int mi = 0; mi < 2; ++mi)
#pragma unroll
            for (int nj = 0; nj < 4; ++nj)
                acc[mi][nj] = __builtin_amdgcn_mfma_f32_16x16x32_bf16(af[mi], bfv[nj], acc[mi][nj], 0, 0, 0);
    }
#pragma unroll
    for (int mi = 0; mi < 2; ++mi) {
#pragma unroll
        for (int nj = 0; nj < 4; ++nj) {
            int col = bn + nj * 16 + m16;
            float bv = bias[col];
#pragma unroll
            for (int r = 0; r < 4; ++r) {
                int row = bm + mi * 16 + g * 4 + r;
                out[(size_t)row * DIMM + col] = acc[mi][nj][r] + bv;
            }
        }
    }
}

extern "C" void kernel_launch(void* const* d_in, const int* in_sizes, int n_in,
                              void* d_out, int out_size, void* d_ws, size_t ws_size,
                              hipStream_t stream) {
    (void)in_sizes; (void)n_in; (void)out_size;
    const float* X    = (const float*)d_in[0];
    const float* Wqkv = (const float*)d_in[1];
    const float* Wout = (const float*)d_in[2];
    const float* bout = (const float*)d_in[3];
    float* out = (float*)d_out;

    const size_t TSZ = (size_t)NSEQ * DIMM;  // 3145728
    const size_t fixed = TSZ * 2 * 5 + (size_t)NQKV * DIMM * 2 + (size_t)DIMM * DIMM * 2;
    const size_t per_split = TSZ * 2 + (size_t)HEADS * NSEQ * 4;   // bf16 Opart + f32 Lpart
    const int nsplit = (ws_size >= fixed + 4 * per_split) ? 4 : 2;

    unsigned char* p = (unsigned char*)d_ws;
    ushort_t* Ap  = (ushort_t*)p; p += TSZ * 2;
    ushort_t* Wqp = (ushort_t*)p; p += (size_t)NQKV * DIMM * 2;
    ushort_t* Wop = (ushort_t*)p; p += (size_t)DIMM * DIMM * 2;
    ushort_t* Qp  = (ushort_t*)p; p += TSZ * 2;
    ushort_t* Kp  = (ushort_t*)p; p += TSZ * 2;
    ushort_t* Vp  = (ushort_t*)p; p += TSZ * 2;
    ushort_t* Xap = (ushort_t*)p; p += TSZ * 2;
    ushort_t* Opart = (ushort_t*)p; p += (size_t)nsplit * TSZ * 2;
    float* Lpart  = (float*)p;

    const int niter = (NSEQ / 64) / nsplit;

    prep_kernel<<<CVT_BLOCKS + PW1_BLOCKS + PW2_BLOCKS, 256, 0, stream>>>(X, Wqkv, Wout, Ap, Wqp, Wop);
    qkv_gemm_kernel<<<dim3(576), 256, 0, stream>>>(Ap, Wqp, Qp, Kp, Vp);
    attn_kernel<<<dim3((NSEQ / 128) * HEADS * nsplit), 128, 0, stream>>>(Qp, Kp, Vp, Opart, Lpart, niter);
    merge_kernel<<<TSZ / 4 / 256, 256, 0, stream>>>(Opart, Lpart, Xap, nsplit);
    out_gemm_kernel<<<dim3(DIMM / 64, NSEQ / 32), 64, 0, stream>>>(Xap, Wop, bout, out);
}